// Round 7
// baseline (750.900 us; speedup 1.0000x reference)
//
#include <hip/hip_runtime.h>
#include <cstdint>
#include <cstddef>

typedef unsigned short u16;
typedef __attribute__((ext_vector_type(8))) short short8;
typedef __attribute__((ext_vector_type(4))) float f32x4;

// ---------- bf16 helpers (OCP bf16 = top 16 bits of fp32, RNE) ----------
__device__ __forceinline__ float bf2f(u16 u) {
  union { uint32_t u; float f; } x; x.u = ((uint32_t)u) << 16; return x.f;
}
__device__ __forceinline__ u16 f2bf(float f) {
  union { float f; uint32_t u; } x; x.f = f;
  uint32_t r = x.u + 0x7FFFu + ((x.u >> 16) & 1u);
  return (u16)(r >> 16);
}
__device__ __forceinline__ float silu_f(float x) { return x / (1.f + __expf(-x)); }

// async global->LDS, 16 B per lane; LDS dst = wave-uniform base + lane*16
__device__ __forceinline__ void glds16(const u16* g, u16* l) {
  __builtin_amdgcn_global_load_lds(
      (const __attribute__((address_space(1))) void*)g,
      (__attribute__((address_space(3))) void*)l, 16, 0, 0);
}

#define MFMA16 __builtin_amdgcn_mfma_f32_16x16x32_bf16

// ---------- merged weight conversions ----------
__global__ void cvt2_kernel(const float* __restrict__ in0, u16* __restrict__ out0, int n0,
                            const float* __restrict__ in1, u16* __restrict__ out1, int n1) {
  int i = (blockIdx.x * 256 + threadIdx.x) * 4;
  const float* in; u16* out;
  if (i < n0) { in = in0 + i; out = out0 + i; }
  else { i -= n0; if (i >= n1) return; in = in1 + i; out = out1 + i; }
  float4 v = *(const float4*)in;
  ushort4 o; o.x = f2bf(v.x); o.y = f2bf(v.y); o.z = f2bf(v.z); o.w = f2bf(v.w);
  *(ushort4*)out = o;
}

__global__ void cvt3_kernel(const float* __restrict__ w12, u16* __restrict__ W1, u16* __restrict__ W2,
                            const float* __restrict__ w3, u16* __restrict__ W3) {
  int i = blockIdx.x * 256 + threadIdx.x;
  const int n1 = 2816 * 1024;
  const int n3 = 1024 * 2816;
  if (i < n1) {
    int r = i >> 10, c = i & 1023;
    W1[i] = f2bf(r < 2730 ? w12[(size_t)r * 1024 + c] : 0.f);
  } else if (i < 2 * n1) {
    int j = i - n1; int r = j >> 10, c = j & 1023;
    W2[j] = f2bf(r < 2730 ? w12[(size_t)(r + 2730) * 1024 + c] : 0.f);
  } else {
    int j = i - 2 * n1; if (j >= n3) return;
    int r = j / 2816, c = j - r * 2816;
    W3[j] = f2bf(c < 2730 ? w3[(size_t)r * 2730 + c] : 0.f);
  }
}

// ---------- mods = silu(c) @ ada_w.T + ada_b ----------
__global__ void mods_kernel(const float* __restrict__ c, const float* __restrict__ ada_w,
                            const float* __restrict__ ada_b, float* __restrict__ mods) {
  int j = blockIdx.x * 4 + (threadIdx.x >> 6);
  int lane = threadIdx.x & 63;
  float a0 = 0.f, a1 = 0.f;
  for (int k = lane; k < 1024; k += 64) {
    float w = ada_w[(size_t)j * 1024 + k];
    a0 += silu_f(c[k]) * w;
    a1 += silu_f(c[1024 + k]) * w;
  }
  #pragma unroll
  for (int off = 32; off > 0; off >>= 1) { a0 += __shfl_down(a0, off); a1 += __shfl_down(a1, off); }
  if (lane == 0) {
    float bb = ada_b[j];
    mods[j] = a0 + bb;
    mods[9216 + j] = a1 + bb;
  }
}

// ---------- rmsnorm(D=1024) * (1+sc) + sh  -> bf16 rows; optional (t,l) transpose ----------
__global__ __launch_bounds__(256) void norm_mod_kernel(
    const float* __restrict__ X, u16* __restrict__ Y,
    const float* __restrict__ nw, const float* __restrict__ mods,
    int sh_idx, int transpose) {
  int row = blockIdx.x;
  int b = row >> 12;
  int in_row;
  if (transpose) { int rem = row & 4095; int l = rem >> 4, t = rem & 15; in_row = (b << 12) + (t << 8) + l; }
  else in_row = row;
  int tid = threadIdx.x;
  float4 v = ((const float4*)(X + (size_t)in_row * 1024))[tid];
  float ss = v.x * v.x + v.y * v.y + v.z * v.z + v.w * v.w;
  #pragma unroll
  for (int off = 32; off > 0; off >>= 1) ss += __shfl_down(ss, off);
  __shared__ float red[4];
  if ((tid & 63) == 0) red[tid >> 6] = ss;
  __syncthreads();
  float rms = rsqrtf((red[0] + red[1] + red[2] + red[3]) * (1.f / 1024.f) + 1e-6f);
  const float* mb = mods + (size_t)b * 9216 + (size_t)sh_idx * 1024;
  float4 sh = ((const float4*)mb)[tid];
  float4 sc = ((const float4*)(mb + 1024))[tid];
  float4 w  = ((const float4*)nw)[tid];
  ushort4 o;
  o.x = f2bf(v.x * rms * w.x * (1.f + sc.x) + sh.x);
  o.y = f2bf(v.y * rms * w.y * (1.f + sc.y) + sh.y);
  o.z = f2bf(v.z * rms * w.z * (1.f + sc.z) + sh.z);
  o.w = f2bf(v.w * rms * w.w * (1.f + sc.w) + sh.w);
  ((ushort4*)(Y + (size_t)row * 1024))[tid] = o;
}

// =====================================================================
// 256-tile GEMM machinery, round-7 structure:
//   - double buffer; tile u+1 staged into NXT at the TOP of iter u
//     (writes never touch the buffer being read -> no drain needed;
//      issue->wait distance = one full iteration)
//   - ONE raw s_barrier per K-tile, preceded by explicit
//     s_waitcnt lgkmcnt(0) (pins "reads consumed before barrier", which
//     makes next-iter restaging of this buffer safe) and s_waitcnt
//     vmcnt(0) (own staging, issued a full iter ago -> ~free)
//   - NO empty "memory"-clobber fences: __syncthreads-style full drains
//     (vmcnt0+lgkmcnt0 before every barrier) were serializing the pipes.
// LDS slot = 16KB: row-major [128][64] bf16, col ^= (row&7)<<3 bank swizzle.
// glds writes linearly; swizzle applied by pre-swizzling the GLOBAL source col.
// =====================================================================
#define CHK2(b, s) (((b) * 4 + (s)) << 13)
#define CHK3(b, s) (((b) * 3 + (s)) << 13)

__device__ __forceinline__ void stage_half(const u16* __restrict__ gp, int ldk,
                                           int row_base, int k0,
                                           u16* Sbase, int slot_u16,
                                           int wid, int srow, int scol) {
  #pragma unroll
  for (int c = 0; c < 2; c++) {
    int row = c * 64 + wid * 8 + srow;
    glds16(gp + (size_t)(row_base + row) * ldk + (k0 + scol),
           Sbase + slot_u16 + c * 4096 + wid * 512);
  }
}

// ---------- dense 256x128-tile GEMM, 1 barrier/K-tile, fused epilogues ----------
// MODE 0: fp32 C; MODE 1: bf16 C; MODE 2: out = base + g*(acc+bias) fp32;
// MODE 3: MODE 2 with (b,l,t)->(b,t,l) row transpose.
// 512 threads, 8 waves as 4m x 2n -> per-wave 64x64 output (16 reads / 32 MFMA).
// grid = 32 * (N/128); LDS = 2 buf x 3 slots x 16KB = 96 KB.
template<int MODE>
__global__ __launch_bounds__(512, 2) void gemm256_n128(
    const u16* __restrict__ A, const u16* __restrict__ W,
    const float* __restrict__ bias, void* __restrict__ Cv,
    int K, int ldc,
    const float* __restrict__ base, const float* __restrict__ mods, int gidx) {
  __shared__ u16 S[49152];   // 96 KB
  const int tid = threadIdx.x, wid = tid >> 6, lane = tid & 63;
  const int wm = wid >> 1, wn = wid & 1;        // 4m x 2n wave grid
  const int quad = lane >> 4, r = lane & 15;
  const int bid = blockIdx.x, xcd = bid & 7, l = bid >> 3;
  const int mt = (xcd << 2) | (l & 3), nt = l >> 2;
  const int m0 = mt * 256, n0 = nt * 128;

  const int srow = lane >> 3;
  const int scol = ((lane & 7) ^ srow) << 3;
  const int kx0 = (quad * 8) ^ ((r & 7) << 3);
  const int kx1 = (32 + quad * 8) ^ ((r & 7) << 3);
  const int aslot = wm >> 1;                    // which A slot this wave reads
  const int arow = ((wm & 1) * 64 + r) * 64;    // + f*16*64
  const int brow = (wn * 64 + r) * 64;          // + j*16*64

  f32x4 zero = {0.f, 0.f, 0.f, 0.f};
  f32x4 acc[4][4];
  #pragma unroll
  for (int i = 0; i < 4; i++)
    #pragma unroll
    for (int j = 0; j < 4; j++) acc[i][j] = zero;
  short8 fA[4][2], fB[4][2];

  const int nk = K >> 6;

  // hoisted staging pointers: start at k=64 (tile u+1 for u=0), advance +64/K-tile
  const u16* gA0c0 = A + (size_t)(m0 +       wid * 8 + srow) * K + scol + 64;
  const u16* gA0c1 = A + (size_t)(m0 +  64 + wid * 8 + srow) * K + scol + 64;
  const u16* gA1c0 = A + (size_t)(m0 + 128 + wid * 8 + srow) * K + scol + 64;
  const u16* gA1c1 = A + (size_t)(m0 + 192 + wid * 8 + srow) * K + scol + 64;
  const u16* gBc0  = W + (size_t)(n0 +       wid * 8 + srow) * K + scol + 64;
  const u16* gBc1  = W + (size_t)(n0 +  64 + wid * 8 + srow) * K + scol + 64;

  // prologue: tile0 -> buf0
  stage_half(A, K, m0,       0, S, CHK3(0,0), wid, srow, scol);
  stage_half(A, K, m0 + 128, 0, S, CHK3(0,1), wid, srow, scol);
  stage_half(W, K, n0,       0, S, CHK3(0,2), wid, srow, scol);
  asm volatile("s_waitcnt vmcnt(0)" ::: "memory");
  __builtin_amdgcn_s_barrier();

  for (int u = 0; u < nk; ++u) {
    const int cur = u & 1, nxt = cur ^ 1;
    const int s1 = (u + 1 < nk);
    const u16* cA = S + CHK3(cur, aslot);
    const u16* cB = S + CHK3(cur, 2);

    // stage tile u+1 -> nxt (issued early; waited at iteration end)
    if (s1) {
      u16* Sb = S + nxt * 24576 + wid * 512;
      glds16(gA0c0, Sb);          glds16(gA0c1, Sb + 4096);
      glds16(gA1c0, Sb + 8192);   glds16(gA1c1, Sb + 12288);
      glds16(gBc0,  Sb + 16384);  glds16(gBc1,  Sb + 20480);
      gA0c0 += 64; gA0c1 += 64; gA1c0 += 64; gA1c1 += 64; gBc0 += 64; gBc1 += 64;
    }

    // fragment reads of tile u (async; consumed by MFMA below)
    #pragma unroll
    for (int f = 0; f < 4; f++) {
      fA[f][0] = *(const short8*)(cA + arow + f * 1024 + kx0);
      fA[f][1] = *(const short8*)(cA + arow + f * 1024 + kx1);
    }
    #pragma unroll
    for (int j = 0; j < 4; j++) {
      fB[j][0] = *(const short8*)(cB + brow + j * 1024 + kx0);
      fB[j][1] = *(const short8*)(cB + brow + j * 1024 + kx1);
    }

    __builtin_amdgcn_s_setprio(1);
    #pragma unroll
    for (int f = 0; f < 4; f++)
      #pragma unroll
      for (int j = 0; j < 4; j++) {
        acc[f][j] = MFMA16(fA[f][0], fB[j][0], acc[f][j], 0, 0, 0);
        acc[f][j] = MFMA16(fA[f][1], fB[j][1], acc[f][j], 0, 0, 0);
      }
    __builtin_amdgcn_s_setprio(0);

    asm volatile("s_waitcnt lgkmcnt(0)" ::: "memory");   // reads consumed (free)
    if (s1) asm volatile("s_waitcnt vmcnt(0)" ::: "memory"); // own staging landed
    __builtin_amdgcn_s_barrier();
  }

  float* Cf = (float*)Cv;
  u16* Ch = (u16*)Cv;
  #pragma unroll
  for (int f = 0; f < 4; f++) {
    int row = m0 + wm * 64 + f * 16 + quad * 4;
    #pragma unroll
    for (int j = 0; j < 4; j++) {
      int col = n0 + wn * 64 + j * 16 + r;
      float bv = bias[col];
      #pragma unroll
      for (int rr = 0; rr < 4; rr++) {
        int ri = row + rr;
        float vv = acc[f][j][rr] + bv;
        if (MODE == 0) {
          Cf[(size_t)ri * ldc + col] = vv;
        } else if (MODE == 1) {
          Ch[(size_t)ri * ldc + col] = f2bf(vv);
        } else {
          int ro = ri;
          if (MODE == 3) { int rem = ri & 4095; ro = (ri & ~4095) + ((rem & 15) << 8) + (rem >> 4); }
          int b = ri >> 12;
          float g = mods[(size_t)b * 9216 + (size_t)gidx * 1024 + col];
          Cf[(size_t)ro * 1024 + col] = base[(size_t)ro * 1024 + col] + g * vv;
        }
      }
    }
  }
}

// ---------- fused w12 + SwiGLU, 256x128 tile, 1 barrier/K-tile ----------
// 8 waves 2m x 4n; per-wave 128 rows x 32 cols for BOTH GEMMs (acc1, acc2).
// LDS: 2 buf x 4 slots (A0, A1, W1, W2) x 16KB = 128 KB.
__global__ __launch_bounds__(512, 2) void gemm256_w12(
    const u16* __restrict__ A, const u16* __restrict__ W1, const u16* __restrict__ W2,
    const float* __restrict__ bias, u16* __restrict__ Hb) {
  __shared__ u16 S[65536];
  const int tid = threadIdx.x, wid = tid >> 6, lane = tid & 63;
  const int wm = wid >> 2, wn = wid & 3;
  const int quad = lane >> 4, r = lane & 15;
  const int bid = blockIdx.x, xcd = bid & 7, l = bid >> 3;
  const int mt = (xcd << 2) | (l & 3), nt = l >> 2;   // nt in [0,22)
  const int m0 = mt * 256, n0 = nt * 128;

  const int srow = lane >> 3;
  const int scol = ((lane & 7) ^ srow) << 3;
  const int kx0 = (quad * 8) ^ ((r & 7) << 3);
  const int kx1 = (32 + quad * 8) ^ ((r & 7) << 3);
  const int arow = (wm * 64 + r) * 64;
  const int brow = (wn * 32 + r) * 64;
  const int K = 1024, nk = 16;

  f32x4 zero = {0.f, 0.f, 0.f, 0.f};
  f32x4 acc1[8][2], acc2[8][2];
  #pragma unroll
  for (int i = 0; i < 8; i++)
    #pragma unroll
    for (int j = 0; j < 2; j++) { acc1[i][j] = zero; acc2[i][j] = zero; }
  short8 fA[4][2], fW1[2][2], fW2[2][2];

  // hoisted staging pointers (k starts at 64 = tile u+1 for u=0)
  const u16* gA0c0 = A  + (size_t)(m0 +       wid * 8 + srow) * K + scol + 64;
  const u16* gA0c1 = A  + (size_t)(m0 +  64 + wid * 8 + srow) * K + scol + 64;
  const u16* gA1c0 = A  + (size_t)(m0 + 128 + wid * 8 + srow) * K + scol + 64;
  const u16* gA1c1 = A  + (size_t)(m0 + 192 + wid * 8 + srow) * K + scol + 64;
  const u16* gW1c0 = W1 + (size_t)(n0 +       wid * 8 + srow) * K + scol + 64;
  const u16* gW1c1 = W1 + (size_t)(n0 +  64 + wid * 8 + srow) * K + scol + 64;
  const u16* gW2c0 = W2 + (size_t)(n0 +       wid * 8 + srow) * K + scol + 64;
  const u16* gW2c1 = W2 + (size_t)(n0 +  64 + wid * 8 + srow) * K + scol + 64;

  // prologue: tile0 -> buf0
  stage_half(A,  K, m0,       0, S, CHK2(0,0), wid, srow, scol);
  stage_half(A,  K, m0 + 128, 0, S, CHK2(0,1), wid, srow, scol);
  stage_half(W1, K, n0,       0, S, CHK2(0,2), wid, srow, scol);
  stage_half(W2, K, n0,       0, S, CHK2(0,3), wid, srow, scol);
  asm volatile("s_waitcnt vmcnt(0)" ::: "memory");
  __builtin_amdgcn_s_barrier();

  for (int u = 0; u < nk; ++u) {
    const int cur = u & 1, nxt = cur ^ 1;
    const int s1 = (u + 1 < nk);
    const u16* cA0 = S + CHK2(cur, 0);
    const u16* cA1 = S + CHK2(cur, 1);
    const u16* cW1 = S + CHK2(cur, 2);
    const u16* cW2 = S + CHK2(cur, 3);

    // stage tile u+1 -> nxt (issued early)
    if (s1) {
      u16* Sb = S + nxt * 32768 + wid * 512;
      glds16(gA0c0, Sb);          glds16(gA0c1, Sb + 4096);
      glds16(gA1c0, Sb + 8192);   glds16(gA1c1, Sb + 12288);
      glds16(gW1c0, Sb + 16384);  glds16(gW1c1, Sb + 20480);
      glds16(gW2c0, Sb + 24576);  glds16(gW2c1, Sb + 28672);
      gA0c0 += 64; gA0c1 += 64; gA1c0 += 64; gA1c1 += 64;
      gW1c0 += 64; gW1c1 += 64; gW2c0 += 64; gW2c1 += 64;
    }

    // reads: A-half0, W1, W2
    #pragma unroll
    for (int f = 0; f < 4; f++) {
      fA[f][0] = *(const short8*)(cA0 + arow + f * 1024 + kx0);
      fA[f][1] = *(const short8*)(cA0 + arow + f * 1024 + kx1);
    }
    #pragma unroll
    for (int j = 0; j < 2; j++) {
      fW1[j][0] = *(const short8*)(cW1 + brow + j * 1024 + kx0);
      fW1[j][1] = *(const short8*)(cW1 + brow + j * 1024 + kx1);
      fW2[j][0] = *(const short8*)(cW2 + brow + j * 1024 + kx0);
      fW2[j][1] = *(const short8*)(cW2 + brow + j * 1024 + kx1);
    }

    __builtin_amdgcn_s_setprio(1);
    #pragma unroll
    for (int f = 0; f < 4; f++)
      #pragma unroll
      for (int j = 0; j < 2; j++) {
        acc1[f][j] = MFMA16(fA[f][0], fW1[j][0], acc1[f][j], 0, 0, 0);
        acc1[f][j] = MFMA16(fA[f][1], fW1[j][1], acc1[f][j], 0, 0, 0);
        acc2[f][j] = MFMA16(fA[f][0], fW2[j][0], acc2[f][j], 0, 0, 0);
        acc2[f][j] = MFMA16(fA[f][1], fW2[j][1], acc2[f][j], 0, 0, 0);
      }
    __builtin_amdgcn_s_setprio(0);

    // reads: A-half1 (reuses fA; no barrier needed — data deps order it)
    #pragma unroll
    for (int f = 0; f < 4; f++) {
      fA[f][0] = *(const short8*)(cA1 + arow + f * 1024 + kx0);
      fA[f][1] = *(const short8*)(cA1 + arow + f * 1024 + kx1);
    }

    __builtin_amdgcn_s_setprio(1);
    #pragma unroll
    for (int f = 0; f < 4; f++)
      #pragma unroll
      for (int j = 0; j < 2; j++) {
        acc1[4 + f][j] = MFMA16(fA[f][0], fW1[j][0], acc1[4 + f][j], 0, 0, 0);
        acc1[4 + f][j] = MFMA16(fA[f][1], fW1[j][1], acc1[4 + f][j], 0, 0, 0);
        acc2[4 + f][j] = MFMA16(fA[f][0], fW2[j][0], acc2[4 + f][j], 0, 0, 0);
        acc2[4 + f][j] = MFMA16(fA[f][1], fW2[j][1], acc2[4 + f][j], 0, 0, 0);
      }
    __builtin_amdgcn_s_setprio(0);

    asm volatile("s_waitcnt lgkmcnt(0)" ::: "memory");
    if (s1) asm volatile("s_waitcnt vmcnt(0)" ::: "memory");
    __builtin_amdgcn_s_barrier();
  }

  #pragma unroll
  for (int f = 0; f < 8; f++) {
    int row = m0 + (f >> 2) * 128 + wm * 64 + (f & 3) * 16 + quad * 4;
    #pragma unroll
    for (int j = 0; j < 2; j++) {
      int col = n0 + wn * 32 + j * 16 + r;
      float b1 = (col < 2730) ? bias[col] : 0.f;
      float b2 = (col < 2730) ? bias[2730 + col] : 0.f;
      #pragma unroll
      for (int rr = 0; rr < 4; rr++) {
        float h1 = acc1[f][j][rr] + b1;
        float h2 = acc2[f][j][rr] + b2;
        Hb[(size_t)(row + rr) * 2816 + col] = f2bf(silu_f(h1) * h2);
      }
    }
  }
}

// ---------- MFMA flash attention, spatial: seq=256, hd=64 ----------
// 512 threads per block, both q-halves in one block; threads 0-255 prep K
// (rmsnorm+rope), 256-511 copy V transposed.
#define KSS 72
#define VSS 264
#define PSS 40
__global__ __launch_bounds__(512) void attn_s_mfma(
    const u16* __restrict__ QKV,
    const float* __restrict__ qn_w, const float* __restrict__ kn_w,
    const float* __restrict__ cosT, const float* __restrict__ sinT,
    u16* __restrict__ AO) {
  __shared__ u16 Ks[256 * KSS];
  __shared__ u16 Vt[64 * VSS];
  __shared__ u16 Pl[8 * 32 * PSS];
  int pair = blockIdx.x;
  int s = pair >> 4, h = pair & 15;
  int tid = threadIdx.x, wid = tid >> 6, lane = tid & 63;
  int quad = lane >> 4, r = lane & 15;

  if (tid < 256) {
    int j = tid;
    size_t rowb = ((size_t)(s * 256 + j)) * 3072 + (size_t)h * 64;
    const short8* kr = (const short8*)(QKV + rowb + 1024);
    float xk[64]; float ssq = 0.f;
    #pragma unroll
    for (int cg = 0; cg < 8; cg++) {
      short8 kk = kr[cg];
      #pragma unroll
      for (int e = 0; e < 8; e++) { float v = bf2f((u16)kk[e]); xk[cg * 8 + e] = v; ssq += v * v; }
    }
    float rms = rsqrtf(ssq * (1.f / 64.f) + 1e-6f);
    short8 kq[8];
    #pragma unroll
    for (int d = 0; d < 32; d++) {
      float a = xk[d] * rms * kn_w[d];
      float b2 = xk[d + 32] * rms * kn_w[d + 32];
      u16 o0 = f2bf(a * cosT[j * 64 + d] - b2 * sinT[j * 64 + d]);
      u16 o1 = f2bf(b2 * cosT[j * 64 + 32 + d] + a * sinT[j * 64 + 32 + d]);
      kq[d >> 3][d & 7] = (short)o0;
      kq[(d + 32) >> 3][d & 7] = (short)o1;
    }
    #pragma unroll
    for (int cg = 0; cg < 8; cg++) *(short8*)(Ks + j * KSS + cg * 8) = kq[cg];
  } else {
    int j = tid - 256;
    size_t rowb = ((size_t)(s * 256 + j)) * 3072 + (size_t)h * 64;
    const short8* vr = (const short8*)(QKV + rowb + 2048);
    #pragma unroll
    for (int cg = 0; cg < 8; cg++) {
      short8 vv = vr[cg];
      #pragma unroll
      for (int e = 0; e < 8; e++) Vt[(cg * 8 + e) * VSS + j] = (u16)vv[e];
    }
  }

  int qbase = wid * 32;   // 8 waves cover 256 q rows
  short8 qa[2][2];
  float lrow[2][4];
  {
    float qv[2][2][8];
    float ssq[2] = {0.f, 0.f};
    #pragma unroll
    for (int i = 0; i < 2; i++) {
      int grow = s * 256 + qbase + i * 16 + r;
      #pragma unroll
      for (int kk = 0; kk < 2; kk++) {
        short8 qraw = *(const short8*)(QKV + (size_t)grow * 3072 + h * 64 + kk * 32 + quad * 8);
        #pragma unroll
        for (int e = 0; e < 8; e++) { float v = bf2f((u16)qraw[e]); qv[i][kk][e] = v; ssq[i] += v * v; }
      }
    }
    #pragma unroll
    for (int i = 0; i < 2; i++) {
      float sv = ssq[i];
      sv += __shfl_xor(sv, 16);
      sv += __shfl_xor(sv, 32);
      float rms = rsqrtf(sv * (1.f / 64.f) + 1e-6f);
      int qrow = qbase + i * 16 + r;
      #pragma unroll
      for (int e = 0; e < 8; e++) {
        int d0 = quad * 8 + e;
        float a = qv[i][0][e] * rms * qn_w[d0];
        float b2 = qv[i][1][e] * rms * qn_w[d0 + 32];
        qa[i][0][e] = (short)f2bf(a * cosT[qrow * 64 + d0] - b2 * sinT[qrow * 64 + d0]);
        qa[i][1][e] = (short)f2bf(b2 * cosT[qrow * 64 + 32 + d0] + a * sinT[qrow * 64 + 32 + d0]);
      }
    }
  }
  __syncthreads();

  f32x4 zero = {0.f, 0.f, 0.f, 0.f};
  f32x4 acc[2][16];
  #pragma unroll
  for (int i = 0; i < 2; i++)
    #pragma unroll
    for (int j = 0; j < 16; j++) acc[i][j] = zero;
  #pragma unroll
  for (int kk = 0; kk < 2; kk++) {
    #pragma unroll
    for (int j = 0; j < 16; j++) {
      short8 bfr = *(const short8*)(Ks + (j * 16 + r) * KSS + kk * 32 + quad * 8);
      acc[0][j] = MFMA16(qa[0][kk], bfr, acc[0][j], 0, 0, 0);
      acc[1][j] = MFMA16(qa[1][kk], bfr, acc[1][j], 0, 0, 0);
    }
  }

  #pragma unroll
  for (int i = 0; i < 2; i++) {
    #pragma unroll
    for (int rr = 0; rr < 4; rr++) {
      float mx = acc[i][0][rr];
      #pragma unroll
      for (int j = 1; j < 16; j++) mx = fmaxf(mx, acc[i][j][rr]);
      #pragma unroll
      for (int msk = 1; msk < 16; msk <<= 1) mx = fmaxf(mx, __shfl_xor(mx, msk));
      float ls = 0.f;
      #pragma unroll
      for (int j = 0; j < 16; j++) { float p = __expf((acc[i][j][rr] - mx) * 0.125f); acc[i][j][rr] = p; ls += p; }
      #pragma unroll
      for (int msk = 1; msk < 16; msk <<= 1) ls += __shfl_xor(ls, msk);
      lrow[i][rr] = ls;
    }
  }

  f32x4 oacc[2][4];
  #pragma unroll
  for (int i = 0; i < 2; i++)
    #pragma unroll
    for (int j = 0; j < 4; j++) oacc[i][j] = zero;
  u16* plw = Pl + wid * 32 * PSS;
  #pragma unroll
  for (int kk = 0; kk < 8; kk++) {
    #pragma unroll
    for (int i = 0; i < 2; i++)
      #pragma unroll
      for (int jj = 0; jj < 2; jj++) {
        int j = kk * 2 + jj;
        #pragma unroll
        for (int rr = 0; rr < 4; rr++)
          plw[(i * 16 + quad * 4 + rr) * PSS + jj * 16 + r] = f2bf(acc[i][j][rr]);
      }
    short8 pa0 = *(const short8*)(plw + r * PSS + quad * 8);
    short8 pa1 = *(const short8*)(plw + (16 + r) * PSS + quad * 8);
    #pragma unroll
    for (int j4 = 0; j4 < 4; j4++) {
      short8 vfr = *(const short8*)(Vt + (j4 * 16 + r) * VSS + kk * 32 + quad * 8);
      oacc[0][j4] = MFMA16(pa0, vfr, oacc[0][j4], 0, 0, 0);
      oacc[1][j4] = MFMA16(pa1, vfr, oacc[1][j4], 0, 0, 0);
    }
  }

  #pragma unroll
  for (int i = 0; i < 2; i++) {
    #pragma unroll
    for (int rr = 0; rr < 4; rr++) {
      float inv = 1.f / lrow[i][rr];
      int row = s * 256 + qbase + i * 16 + quad * 4 + rr;
      #pragma unroll
      for (int j4 = 0; j4 < 4; j4++)
        AO[(size_t)row * 1024 + h * 64 + j4 * 16 + r] = f2bf(oacc[i][j4][rr] * inv);
    }
  }
}

// ---------- temporal attention: seq=16, block per (b,l), thread = (head, t) ----------
__global__ __launch_bounds__(256) void attn_t_kernel(
    const u16* __restrict__ QKV,
    const float* __restrict__ qn_w, const float* __restrict__ kn_w,
    const float* __restrict__ cosT, const float* __restrict__ sinT,
    u16* __restrict__ AO) {
  __shared__ u16 kb[256 * 64];
  __shared__ u16 vb[256 * 64];
  int bl = blockIdx.x;
  int tid = threadIdx.x;
  int h = tid >> 4, t = tid & 15;
  size_t rowbase = ((size_t)(bl * 16 + t)) * 3072;
  int slot = h * 16 + t;
  {
    const u16* kr = QKV + rowbase + 1024 + h * 64;
    float xk[64]; float ss = 0.f;
    #pragma unroll
    for (int d = 0; d < 64; d++) { xk[d] = bf2f(kr[d]); ss += xk[d] * xk[d]; }
    float rms = rsqrtf(ss * (1.f / 64.f) + 1e-6f);
    #pragma unroll
    for (int d = 0; d < 64; d++) xk[d] *= rms * kn_w[d];
    #pragma unroll
    for (int d = 0; d < 32; d++) {
      float a = xk[d], bb = xk[d + 32];
      kb[slot * 64 + d]      = f2bf(a * cosT[t * 64 + d]       - bb * sinT[t * 64 + d]);
      kb[slot * 64 + 32 + d] = f2bf(bb * cosT[t * 64 + 32 + d] + a * sinT[t * 64 + 32 + d]);
    }
    const u16* vr = QKV + rowbase + 2048 + h * 64;
    #pragma unroll
    for (int d = 0; d < 64; d++) vb[slot * 64 + d] = vr[d];
  }
  float q[64];
  {
    const u16* qr = QKV + rowbase + h * 64;
    float ss = 0.f;
    #pragma unroll
    for (int d = 0; d < 64; d++) { q[d] = bf2f(qr[d]); ss += q[d] * q[d]; }
    float rms = rsqrtf(ss * (1.f / 64.f) + 1e-6f);
    #pragma unroll
    for (int d = 0; d < 64; d++) q[d] *= rms * qn_w[d];
    #pragma unroll
    for (int d = 0; d < 32; d++) {
      float a = q[d], bb = q[d + 32];
      q[d]      = a * cosT[t * 64 + d]       - bb * sinT[t * 64 + d];
      q[d + 32] = bb * cosT[t * 64 + 32 + d] + a * sinT[t * 64 + 32 + d];
    }
  }
  __syncthreads();
  float scv[16]; float mx = -1e30f;
  #pragma unroll
  for (int j = 0; j < 16; j++) {
    float sc = 0.f;
    const short8* krow = (const short8*)(kb + (h * 16 + j) * 64);
    #pragma unroll
    for (int vv = 0; vv < 8; vv++) {
      short8 kk = krow[vv];
      #pragma unroll
      for (int e = 0; e < 8; e++) sc += q[vv * 8 + e] * bf2f((u16)kk[e]);
    }
    scv[j] = sc * 0.125f;
    mx = fmaxf(mx, scv[j]);
  }
  float ssum = 0.f;
  #pragma unroll
  for (int j = 0; j < 16; j++) { scv[j] = __expf(scv[j] - mx); ssum += scv[j]; }
  float inv = 1.f / ssum;
  float o[64];
  #pragma unroll
  for (int d = 0; d < 64; d++) o[d] = 0.f;
  #pragma unroll
  for (int j = 0; j < 16; j++) {
    const short8* vrow = (const short8*)(vb + (h * 16 + j) * 64);
    #pragma unroll
    for (int vv = 0; vv < 8; vv++) {
      short8 vk = vrow[vv];
      #pragma unroll
      for (int e = 0; e < 8; e++) o[vv * 8 + e] += scv[j] * bf2f((u16)vk[e]);
    }
  }
  u16* op = AO + ((size_t)(bl * 16 + t)) * 1024 + h * 64;
  #pragma unroll
  for (int d = 0; d < 64; d++) op[d] = f2bf(o[d] * inv);
}

// =====================================================================
extern "C" void kernel_launch(void* const* d_in, const int* in_sizes, int n_in,
                              void* d_out, int out_size, void* d_ws, size_t ws_size,
                              hipStream_t stream) {
  const float* x        = (const float*)d_in[0];
  const float* c        = (const float*)d_in[1];
  const float* cos_s    = (const float*)d_in[2];
  const float* sin_s    = (const float*)d_in[3];
  const float* cos_t    = (const float*)d_in[4];
  const float* sin_t    = (const float*)d_in[5];
  const float* norm1w   = (const float*)d_in[6];
  const float* norm2w   = (const float*)d_in[7];
  const float* norm3w   = (const float*)d_in[8];
  const float* qkv_s_w  = (const float*)d_in[9];
  const float* qkv_s_b  = (const float*)d_in[10];
  const float* qn_s_w   = (const float*)d_in[11];
  const float* kn_s_w   = (const float*)d_in[12];
  const float* proj_s_w = (const float*)d_in[13];
  const float* proj_s_b = (const float*)d_in[14];
  const float* qkv_t_w  = (const float*)d_in[15];
  const float* qkv_t_b  = (const float*)d_in[16];
  const float* qn_t_w   = (const float*)d_in[17];
  const float* kn_t_w   = (const float*)d_in[18];
  const float* proj_t_w = (const float*)d_in[19];
  const float* proj_t_b = (const float*)d_in[20];
  const float* w12_w    = (const float*)d_in[21];
  const float* w12_b    = (const float*)d_in[22];
  const float* w3_w     = (const float*)d_in[23];
  const float* w3_b     = (const float*)d_in[24];
  const float* ada_w    = (const float*)d_in[25];
  const float* ada_b    = (const float*)d_in[26];
  float* out = (float*)d_out;

  // ---- workspace layout (unchanged) ----
  char* wsp = (char*)d_ws;
  size_t off = 0;
  auto alloc = [&](size_t bytes) { size_t p = off; off += (bytes + 255) & ~(size_t)255; return p; };
  float* modsb = (float*)(wsp + alloc(2 * 9216 * 4));
  u16*   BIG   = (u16*)  (wsp + alloc((size_t)8192 * 3072 * 2));  // QKV (st1,2) / Hb 8192x2816 (st3)
  char*  XnP   = (char*) (wsp + alloc((size_t)8192 * 1024 * 4));  // Xn bf16
  u16*   AO    = (u16*)  (wsp + alloc((size_t)8192 * 1024 * 2));
  u16*   Wq    = (u16*)  (wsp + alloc((size_t)3072 * 1024 * 2));
  u16*   Wp    = (u16*)  (wsp + alloc((size_t)2816 * 1024 * 2));
  u16*   W3b   = (u16*)  (wsp + alloc((size_t)1024 * 2816 * 2));
  u16* W1p = Wq;
  u16* W2p = Wp;
  u16* Xn  = (u16*)XnP;
  float* Xcur = out;   // residual stream lives in d_out

  dim3 blk(256);
  dim3 blk512(512);
  mods_kernel<<<2304, blk, 0, stream>>>(c, ada_w, ada_b, modsb);

  // ---- stage 1: spatial attention ----
  {
    int n0 = 3072 * 1024, n1 = 1024 * 1024;
    cvt2_kernel<<<(n0 + n1) / 1024, blk, 0, stream>>>(qkv_s_w, Wq, n0, proj_s_w, Wp, n1);
  }
  norm_mod_kernel<<<8192, blk, 0, stream>>>(x, Xn, norm1w, modsb, 0, 0);
  // QKV: N=3072 -> 32 x 24 = 768 blocks = 3 exact dispatch rounds
  gemm256_n128<1><<<dim3(32 * 24), blk512, 0, stream>>>(Xn, Wq, qkv_s_b, BIG, 1024, 3072, nullptr, nullptr, 0);
  attn_s_mfma<<<dim3(512), blk512, 0, stream>>>(BIG, qn_s_w, kn_s_w, cos_s, sin_s, AO);
  // proj + residual fused: Xcur = x + g2 * (AO @ Wp^T + b)
  gemm256_n128<2><<<dim3(32 * 8), blk512, 0, stream>>>(AO, Wp, proj_s_b, Xcur, 1024, 1024, x, modsb, 2);

  // ---- stage 2: temporal attention (rows in (b,l,t) order) ----
  {
    int n0 = 3072 * 1024, n1 = 1024 * 1024;
    cvt2_kernel<<<(n0 + n1) / 1024, blk, 0, stream>>>(qkv_t_w, Wq, n0, proj_t_w, Wp, n1);
  }
  norm_mod_kernel<<<8192, blk, 0, stream>>>(Xcur, Xn, norm2w, modsb, 3, 1);
  gemm256_n128<1><<<dim3(32 * 24), blk512, 0, stream>>>(Xn, Wq, qkv_t_b, BIG, 1024, 3072, nullptr, nullptr, 0);
  attn_t_kernel<<<512, blk, 0, stream>>>(BIG, qn_t_w, kn_t_w, cos_t, sin_t, AO);
  // proj + residual fused with (b,l,t)->(b,t,l) transpose: Xcur = Xcur + g5 * T(proj)
  gemm256_n128<3><<<dim3(32 * 8), blk512, 0, stream>>>(AO, Wp, proj_t_b, Xcur, 1024, 1024, Xcur, modsb, 5);

  // ---- stage 3: SwiGLU MLP (HFF 2730 padded to 2816) ----
  {
    int tot = 2 * 2816 * 1024 + 1024 * 2816;
    cvt3_kernel<<<(tot + 255) / 256, blk, 0, stream>>>(w12_w, W1p, W2p, w3_w, W3b);
  }
  norm_mod_kernel<<<8192, blk, 0, stream>>>(Xcur, Xn, norm3w, modsb, 6, 0);
  gemm256_w12<<<dim3(32 * 22), blk512, 0, stream>>>(Xn, W1p, W2p, w12_b, BIG);
  // w3 + residual fused: out = Xcur + g8 * (Hb @ W3^T + b)
  gemm256_n128<2><<<dim3(32 * 8), blk512, 0, stream>>>(BIG, W3b, w3_b, out, 2816, 1024, Xcur, modsb, 8);
}

// Round 8
// 675.510 us; speedup vs baseline: 1.1116x; 1.1116x over previous
//
#include <hip/hip_runtime.h>
#include <cstdint>
#include <cstddef>

typedef unsigned short u16;
typedef __attribute__((ext_vector_type(8))) short short8;
typedef __attribute__((ext_vector_type(4))) float f32x4;

// ---------- bf16 helpers (OCP bf16 = top 16 bits of fp32, RNE) ----------
__device__ __forceinline__ float bf2f(u16 u) {
  union { uint32_t u; float f; } x; x.u = ((uint32_t)u) << 16; return x.f;
}
__device__ __forceinline__ u16 f2bf(float f) {
  union { float f; uint32_t u; } x; x.f = f;
  uint32_t r = x.u + 0x7FFFu + ((x.u >> 16) & 1u);
  return (u16)(r >> 16);
}
__device__ __forceinline__ float silu_f(float x) { return x / (1.f + __expf(-x)); }

// async global->LDS, 16 B per lane; LDS dst = wave-uniform base + lane*16
__device__ __forceinline__ void glds16(const u16* g, u16* l) {
  __builtin_amdgcn_global_load_lds(
      (const __attribute__((address_space(1))) void*)g,
      (__attribute__((address_space(3))) void*)l, 16, 0, 0);
}

#define MFMA16 __builtin_amdgcn_mfma_f32_16x16x32_bf16

// raw barrier with compiler memory fences only.
__device__ __forceinline__ void wg_barrier() {
  asm volatile("" ::: "memory");
  __builtin_amdgcn_s_barrier();
  asm volatile("" ::: "memory");
}

// ---------- merged weight conversions ----------
__global__ void cvt2_kernel(const float* __restrict__ in0, u16* __restrict__ out0, int n0,
                            const float* __restrict__ in1, u16* __restrict__ out1, int n1) {
  int i = (blockIdx.x * 256 + threadIdx.x) * 4;
  const float* in; u16* out;
  if (i < n0) { in = in0 + i; out = out0 + i; }
  else { i -= n0; if (i >= n1) return; in = in1 + i; out = out1 + i; }
  float4 v = *(const float4*)in;
  ushort4 o; o.x = f2bf(v.x); o.y = f2bf(v.y); o.z = f2bf(v.z); o.w = f2bf(v.w);
  *(ushort4*)out = o;
}

__global__ void cvt3_kernel(const float* __restrict__ w12, u16* __restrict__ W1, u16* __restrict__ W2,
                            const float* __restrict__ w3, u16* __restrict__ W3) {
  int i = blockIdx.x * 256 + threadIdx.x;
  const int n1 = 2816 * 1024;
  const int n3 = 1024 * 2816;
  if (i < n1) {
    int r = i >> 10, c = i & 1023;
    W1[i] = f2bf(r < 2730 ? w12[(size_t)r * 1024 + c] : 0.f);
  } else if (i < 2 * n1) {
    int j = i - n1; int r = j >> 10, c = j & 1023;
    W2[j] = f2bf(r < 2730 ? w12[(size_t)(r + 2730) * 1024 + c] : 0.f);
  } else {
    int j = i - 2 * n1; if (j >= n3) return;
    int r = j / 2816, c = j - r * 2816;
    W3[j] = f2bf(c < 2730 ? w3[(size_t)r * 2730 + c] : 0.f);
  }
}

// ---------- mods = silu(c) @ ada_w.T + ada_b ----------
__global__ void mods_kernel(const float* __restrict__ c, const float* __restrict__ ada_w,
                            const float* __restrict__ ada_b, float* __restrict__ mods) {
  int j = blockIdx.x * 4 + (threadIdx.x >> 6);
  int lane = threadIdx.x & 63;
  float a0 = 0.f, a1 = 0.f;
  for (int k = lane; k < 1024; k += 64) {
    float w = ada_w[(size_t)j * 1024 + k];
    a0 += silu_f(c[k]) * w;
    a1 += silu_f(c[1024 + k]) * w;
  }
  #pragma unroll
  for (int off = 32; off > 0; off >>= 1) { a0 += __shfl_down(a0, off); a1 += __shfl_down(a1, off); }
  if (lane == 0) {
    float bb = ada_b[j];
    mods[j] = a0 + bb;
    mods[9216 + j] = a1 + bb;
  }
}

// ---------- rmsnorm(D=1024) * (1+sc) + sh  -> bf16 rows; optional (t,l) transpose ----------
__global__ __launch_bounds__(256) void norm_mod_kernel(
    const float* __restrict__ X, u16* __restrict__ Y,
    const float* __restrict__ nw, const float* __restrict__ mods,
    int sh_idx, int transpose) {
  int row = blockIdx.x;
  int b = row >> 12;
  int in_row;
  if (transpose) { int rem = row & 4095; int l = rem >> 4, t = rem & 15; in_row = (b << 12) + (t << 8) + l; }
  else in_row = row;
  int tid = threadIdx.x;
  float4 v = ((const float4*)(X + (size_t)in_row * 1024))[tid];
  float ss = v.x * v.x + v.y * v.y + v.z * v.z + v.w * v.w;
  #pragma unroll
  for (int off = 32; off > 0; off >>= 1) ss += __shfl_down(ss, off);
  __shared__ float red[4];
  if ((tid & 63) == 0) red[tid >> 6] = ss;
  __syncthreads();
  float rms = rsqrtf((red[0] + red[1] + red[2] + red[3]) * (1.f / 1024.f) + 1e-6f);
  const float* mb = mods + (size_t)b * 9216 + (size_t)sh_idx * 1024;
  float4 sh = ((const float4*)mb)[tid];
  float4 sc = ((const float4*)(mb + 1024))[tid];
  float4 w  = ((const float4*)nw)[tid];
  ushort4 o;
  o.x = f2bf(v.x * rms * w.x * (1.f + sc.x) + sh.x);
  o.y = f2bf(v.y * rms * w.y * (1.f + sc.y) + sh.y);
  o.z = f2bf(v.z * rms * w.z * (1.f + sc.z) + sh.z);
  o.w = f2bf(v.w * rms * w.w * (1.f + sc.w) + sh.w);
  ((ushort4*)(Y + (size_t)row * 1024))[tid] = o;
}

// =====================================================================
// 256-tile GEMM machinery, round-6 structure (proven 663us): BIG MFMA
// clusters, 2-3 wg_barrier regions per K-tile, tile u+2 restaged into the
// CURRENT buffer after its last read (barrier-separated).
// LDS slot = 16KB: row-major [128][64] bf16, col ^= (row&7)<<3 bank swizzle.
// glds writes linearly; swizzle applied by pre-swizzling the GLOBAL source col.
// =====================================================================
#define CHK2(b, s) (((b) * 4 + (s)) << 13)
#define CHK3(b, s) (((b) * 3 + (s)) << 13)

__device__ __forceinline__ void stage_half(const u16* __restrict__ gp, int ldk,
                                           int row_base, int k0,
                                           u16* Sbase, int slot_u16,
                                           int wid, int srow, int scol) {
  #pragma unroll
  for (int c = 0; c < 2; c++) {
    int row = c * 64 + wid * 8 + srow;
    glds16(gp + (size_t)(row_base + row) * ldk + (k0 + scol),
           Sbase + slot_u16 + c * 4096 + wid * 512);
  }
}

// ---------- dense 256x128-tile GEMM, 2 barriers/K-tile, fused epilogues ----------
// MODE 0: fp32 C; MODE 1: bf16 C; MODE 2: out = base + g*(acc+bias) fp32;
// MODE 3: MODE 2 with (b,l,t)->(b,t,l) row transpose.
// 512 threads, 8 waves as 4m x 2n -> per-wave 64x64 output (16 reads / 32 MFMA).
// grid = 32 * (N/128); LDS = 2 buf x 3 slots x 16KB = 96 KB.
template<int MODE>
__global__ __launch_bounds__(512, 2) void gemm256_n128(
    const u16* __restrict__ A, const u16* __restrict__ W,
    const float* __restrict__ bias, void* __restrict__ Cv,
    int K, int ldc,
    const float* __restrict__ base, const float* __restrict__ mods, int gidx) {
  __shared__ u16 S[49152];   // 96 KB
  const int tid = threadIdx.x, wid = tid >> 6, lane = tid & 63;
  const int wm = wid >> 1, wn = wid & 1;        // 4m x 2n wave grid
  const int quad = lane >> 4, r = lane & 15;
  const int bid = blockIdx.x, xcd = bid & 7, l = bid >> 3;
  const int mt = (xcd << 2) | (l & 3), nt = l >> 2;
  const int m0 = mt * 256, n0 = nt * 128;

  const int srow = lane >> 3;
  const int scol = ((lane & 7) ^ srow) << 3;
  const int kx0 = (quad * 8) ^ ((r & 7) << 3);
  const int kx1 = (32 + quad * 8) ^ ((r & 7) << 3);
  const int aslot = wm >> 1;                    // which A slot this wave reads
  const int arow = ((wm & 1) * 64 + r) * 64;    // + f*16*64
  const int brow = (wn * 64 + r) * 64;          // + j*16*64

  f32x4 zero = {0.f, 0.f, 0.f, 0.f};
  f32x4 acc[4][4];
  #pragma unroll
  for (int i = 0; i < 4; i++)
    #pragma unroll
    for (int j = 0; j < 4; j++) acc[i][j] = zero;
  short8 fA[4][2], fB[4][2];

  const int nk = K >> 6;

  // hoisted staging pointers: start at k=128 (tile u+2 for u=0), advance +64/K-tile
  const u16* gA0c0 = A + (size_t)(m0 +       wid * 8 + srow) * K + scol + 128;
  const u16* gA0c1 = A + (size_t)(m0 +  64 + wid * 8 + srow) * K + scol + 128;
  const u16* gA1c0 = A + (size_t)(m0 + 128 + wid * 8 + srow) * K + scol + 128;
  const u16* gA1c1 = A + (size_t)(m0 + 192 + wid * 8 + srow) * K + scol + 128;
  const u16* gBc0  = W + (size_t)(n0 +       wid * 8 + srow) * K + scol + 128;
  const u16* gBc1  = W + (size_t)(n0 +  64 + wid * 8 + srow) * K + scol + 128;

  // prologue: tile0 then tile1
  stage_half(A, K, m0,       0, S, CHK3(0,0), wid, srow, scol);
  stage_half(A, K, m0 + 128, 0, S, CHK3(0,1), wid, srow, scol);
  stage_half(W, K, n0,       0, S, CHK3(0,2), wid, srow, scol);
  if (nk > 1) {
    stage_half(A, K, m0,       64, S, CHK3(1,0), wid, srow, scol);
    stage_half(A, K, m0 + 128, 64, S, CHK3(1,1), wid, srow, scol);
    stage_half(W, K, n0,       64, S, CHK3(1,2), wid, srow, scol);
    asm volatile("s_waitcnt vmcnt(6)" ::: "memory");
  } else {
    asm volatile("s_waitcnt vmcnt(0)" ::: "memory");
  }
  __builtin_amdgcn_s_barrier();

  for (int u = 0; u < nk; ++u) {
    const int cur = u & 1;
    const int s1 = (u + 1 < nk), s2 = (u + 2 < nk);
    const u16* cA = S + CHK3(cur, aslot);
    const u16* cB = S + CHK3(cur, 2);

    // region 1: all fragment reads of tile u
    #pragma unroll
    for (int f = 0; f < 4; f++) {
      fA[f][0] = *(const short8*)(cA + arow + f * 1024 + kx0);
      fA[f][1] = *(const short8*)(cA + arow + f * 1024 + kx1);
    }
    #pragma unroll
    for (int j = 0; j < 4; j++) {
      fB[j][0] = *(const short8*)(cB + brow + j * 1024 + kx0);
      fB[j][1] = *(const short8*)(cB + brow + j * 1024 + kx1);
    }
    wg_barrier();   // bar1: all waves' reads of cur complete

    // region 2: stage tile u+2 -> cur, then one 32-MFMA cluster
    if (s2) {
      u16* Sb = S + cur * 24576 + wid * 512;
      glds16(gA0c0, Sb);          glds16(gA0c1, Sb + 4096);
      glds16(gA1c0, Sb + 8192);   glds16(gA1c1, Sb + 12288);
      glds16(gBc0,  Sb + 16384);  glds16(gBc1,  Sb + 20480);
    }
    gA0c0 += 64; gA0c1 += 64; gA1c0 += 64; gA1c1 += 64; gBc0 += 64; gBc1 += 64;
    __builtin_amdgcn_s_setprio(1);
    #pragma unroll
    for (int f = 0; f < 4; f++)
      #pragma unroll
      for (int j = 0; j < 4; j++) {
        acc[f][j] = MFMA16(fA[f][0], fB[j][0], acc[f][j], 0, 0, 0);
        acc[f][j] = MFMA16(fA[f][1], fB[j][1], acc[f][j], 0, 0, 0);
      }
    __builtin_amdgcn_s_setprio(0);
    if (s2)      asm volatile("s_waitcnt vmcnt(6)" ::: "memory");
    else if (s1) asm volatile("s_waitcnt vmcnt(0)" ::: "memory");
    wg_barrier();   // bar2: tile u+1 fully in LDS across all waves
  }

  float* Cf = (float*)Cv;
  u16* Ch = (u16*)Cv;
  #pragma unroll
  for (int f = 0; f < 4; f++) {
    int row = m0 + wm * 64 + f * 16 + quad * 4;
    #pragma unroll
    for (int j = 0; j < 4; j++) {
      int col = n0 + wn * 64 + j * 16 + r;
      float bv = bias[col];
      #pragma unroll
      for (int rr = 0; rr < 4; rr++) {
        int ri = row + rr;
        float vv = acc[f][j][rr] + bv;
        if (MODE == 0) {
          Cf[(size_t)ri * ldc + col] = vv;
        } else if (MODE == 1) {
          Ch[(size_t)ri * ldc + col] = f2bf(vv);
        } else {
          int ro = ri;
          if (MODE == 3) { int rem = ri & 4095; ro = (ri & ~4095) + ((rem & 15) << 8) + (rem >> 4); }
          int b = ri >> 12;
          float g = mods[(size_t)b * 9216 + (size_t)gidx * 1024 + col];
          Cf[(size_t)ro * 1024 + col] = base[(size_t)ro * 1024 + col] + g * vv;
        }
      }
    }
  }
}

// ---------- round-8: 256x128 BK=32 GEMM at 2 blocks/CU (QKV) ----------
// 48 KB LDS (2 buf x 3 slots x 8KB), __launch_bounds__(512,4) caps VGPR at 128
// so TWO blocks co-reside per CU: cross-block wave overlap fills barrier
// stalls (m114 mechanism) that intra-block scheduling cannot.
// LDS slot = [128 rows][32 cols] bf16 (64B rows); bank swizzle: 16B-granule
// g ^= (row>>1)&3 (quad-pattern reads land 2 lanes/4-bank group = free).
// Staging pre-swizzles the global source with the same involution:
// lane l -> row l>>2, source granule (l&3)^((l>>3)&3).
__global__ __launch_bounds__(512, 4) void gemm256_qkv(
    const u16* __restrict__ A, const u16* __restrict__ W,
    const float* __restrict__ bias, u16* __restrict__ C,
    int K, int ldc) {
  __shared__ u16 S[24576];   // 48 KB
  const int tid = threadIdx.x, wid = tid >> 6, lane = tid & 63;
  const int wm = wid >> 1, wn = wid & 1;        // 4m x 2n wave grid
  const int quad = lane >> 4, r = lane & 15;
  const int bid = blockIdx.x, xcd = bid & 7, l = bid >> 3;
  const int mt = (xcd << 2) | (l & 3), nt = l >> 2;
  const int m0 = mt * 256, n0 = nt * 128;

  // staging lane mapping (16 rows x 4 granules per 1KB chunk)
  const int srow16 = lane >> 2;
  const int scol = ((lane & 3) ^ ((lane >> 3) & 3)) * 8;   // u16

  // fragment addresses within a slot (precomputed; granule = quad ^ ((row>>1)&3))
  const int aslot = wm >> 1;
  int addrA[4], addrB[4];
  #pragma unroll
  for (int f = 0; f < 4; f++) {
    int row = (wm & 1) * 64 + f * 16 + r;
    addrA[f] = aslot * 4096 + row * 32 + ((quad ^ ((row >> 1) & 3)) * 8);
  }
  #pragma unroll
  for (int j = 0; j < 4; j++) {
    int row = wn * 64 + j * 16 + r;
    addrB[j] = 2 * 4096 + row * 32 + ((quad ^ ((row >> 1) & 3)) * 8);
  }

  f32x4 zero = {0.f, 0.f, 0.f, 0.f};
  f32x4 acc[4][4];
  #pragma unroll
  for (int i = 0; i < 4; i++)
    #pragma unroll
    for (int j = 0; j < 4; j++) acc[i][j] = zero;
  short8 fA[4], fB[4];

  // per-wave staging pointers (wave wid stages chunk wid of each slot)
  const u16* pA0 = A + (size_t)(m0 +       wid * 16 + srow16) * K + scol;
  const u16* pA1 = A + (size_t)(m0 + 128 + wid * 16 + srow16) * K + scol;
  const u16* pB  = W + (size_t)(n0 +       wid * 16 + srow16) * K + scol;

  // prologue: tile0 -> buf0, tile1 -> buf1
  glds16(pA0,      S +          wid * 512);
  glds16(pA1,      S +  4096 +  wid * 512);
  glds16(pB,       S +  8192 +  wid * 512);
  glds16(pA0 + 32, S + 12288 +          wid * 512);
  glds16(pA1 + 32, S + 12288 +  4096 +  wid * 512);
  glds16(pB  + 32, S + 12288 +  8192 +  wid * 512);
  pA0 += 64; pA1 += 64; pB += 64;
  asm volatile("s_waitcnt vmcnt(0)" ::: "memory");
  __builtin_amdgcn_s_barrier();

  const int nk = K >> 5;
  for (int u = 0; u < nk; ++u) {
    const int cur = u & 1;
    const int s2 = (u + 2 < nk);
    const u16* Sc = S + cur * 12288;

    // region 1: fragment reads of tile u
    #pragma unroll
    for (int f = 0; f < 4; f++) fA[f] = *(const short8*)(Sc + addrA[f]);
    #pragma unroll
    for (int j = 0; j < 4; j++) fB[j] = *(const short8*)(Sc + addrB[j]);
    wg_barrier();   // all waves' reads of cur complete

    // region 2: stage tile u+2 -> cur; 16-MFMA cluster
    if (s2) {
      u16* Sb = S + cur * 12288 + wid * 512;
      glds16(pA0, Sb); glds16(pA1, Sb + 4096); glds16(pB, Sb + 8192);
      pA0 += 32; pA1 += 32; pB += 32;
    }
    __builtin_amdgcn_s_setprio(1);
    #pragma unroll
    for (int f = 0; f < 4; f++)
      #pragma unroll
      for (int j = 0; j < 4; j++)
        acc[f][j] = MFMA16(fA[f], fB[j], acc[f][j], 0, 0, 0);
    __builtin_amdgcn_s_setprio(0);
    wg_barrier();   // clobber drains -> tile u+1 fully in LDS
  }

  #pragma unroll
  for (int f = 0; f < 4; f++) {
    int row = m0 + wm * 64 + f * 16 + quad * 4;
    #pragma unroll
    for (int j = 0; j < 4; j++) {
      int col = n0 + wn * 64 + j * 16 + r;
      float bv = bias[col];
      #pragma unroll
      for (int rr = 0; rr < 4; rr++)
        C[(size_t)(row + rr) * ldc + col] = f2bf(acc[f][j][rr] + bv);
    }
  }
}

// ---------- fused w12 + SwiGLU, 256x128 tile, 3 barriers/K-tile ----------
// 8 waves 2m x 4n; per-wave 128 rows x 32 cols for BOTH GEMMs (acc1, acc2).
// LDS: 2 buf x 4 slots (A0, A1, W1, W2) x 16KB = 128 KB.
__global__ __launch_bounds__(512, 2) void gemm256_w12(
    const u16* __restrict__ A, const u16* __restrict__ W1, const u16* __restrict__ W2,
    const float* __restrict__ bias, u16* __restrict__ Hb) {
  __shared__ u16 S[65536];
  const int tid = threadIdx.x, wid = tid >> 6, lane = tid & 63;
  const int wm = wid >> 2, wn = wid & 3;
  const int quad = lane >> 4, r = lane & 15;
  const int bid = blockIdx.x, xcd = bid & 7, l = bid >> 3;
  const int mt = (xcd << 2) | (l & 3), nt = l >> 2;   // nt in [0,22)
  const int m0 = mt * 256, n0 = nt * 128;

  const int srow = lane >> 3;
  const int scol = ((lane & 7) ^ srow) << 3;
  const int kx0 = (quad * 8) ^ ((r & 7) << 3);
  const int kx1 = (32 + quad * 8) ^ ((r & 7) << 3);
  const int arow = (wm * 64 + r) * 64;
  const int brow = (wn * 32 + r) * 64;
  const int K = 1024, nk = 16;

  f32x4 zero = {0.f, 0.f, 0.f, 0.f};
  f32x4 acc1[8][2], acc2[8][2];
  #pragma unroll
  for (int i = 0; i < 8; i++)
    #pragma unroll
    for (int j = 0; j < 2; j++) { acc1[i][j] = zero; acc2[i][j] = zero; }
  short8 fA[4][2], fW1[2][2], fW2[2][2];

  // hoisted staging pointers (k starts at 128 = tile u+2 for u=0)
  const u16* gA0c0 = A  + (size_t)(m0 +       wid * 8 + srow) * K + scol + 128;
  const u16* gA0c1 = A  + (size_t)(m0 +  64 + wid * 8 + srow) * K + scol + 128;
  const u16* gA1c0 = A  + (size_t)(m0 + 128 + wid * 8 + srow) * K + scol + 128;
  const u16* gA1c1 = A  + (size_t)(m0 + 192 + wid * 8 + srow) * K + scol + 128;
  const u16* gW1c0 = W1 + (size_t)(n0 +       wid * 8 + srow) * K + scol + 128;
  const u16* gW1c1 = W1 + (size_t)(n0 +  64 + wid * 8 + srow) * K + scol + 128;
  const u16* gW2c0 = W2 + (size_t)(n0 +       wid * 8 + srow) * K + scol + 128;
  const u16* gW2c1 = W2 + (size_t)(n0 +  64 + wid * 8 + srow) * K + scol + 128;

  // prologue: tile0 then tile1
  stage_half(A,  K, m0,       0, S, CHK2(0,0), wid, srow, scol);
  stage_half(W1, K, n0,       0, S, CHK2(0,2), wid, srow, scol);
  stage_half(W2, K, n0,       0, S, CHK2(0,3), wid, srow, scol);
  stage_half(A,  K, m0 + 128, 0, S, CHK2(0,1), wid, srow, scol);
  stage_half(A,  K, m0,      64, S, CHK2(1,0), wid, srow, scol);
  stage_half(W1, K, n0,      64, S, CHK2(1,2), wid, srow, scol);
  stage_half(W2, K, n0,      64, S, CHK2(1,3), wid, srow, scol);
  stage_half(A,  K, m0 + 128,64, S, CHK2(1,1), wid, srow, scol);
  asm volatile("s_waitcnt vmcnt(8)" ::: "memory");
  __builtin_amdgcn_s_barrier();

  for (int u = 0; u < nk; ++u) {
    const int cur = u & 1;
    const int s1 = (u + 1 < nk), s2 = (u + 2 < nk);
    const u16* cA0 = S + CHK2(cur, 0);
    const u16* cA1 = S + CHK2(cur, 1);
    const u16* cW1 = S + CHK2(cur, 2);
    const u16* cW2 = S + CHK2(cur, 3);
    u16* Sb = S + cur * 32768 + wid * 512;   // restage base (slots at +0/8192/16384/24576)

    // region 1: read A0 + W1 + W2
    #pragma unroll
    for (int f = 0; f < 4; f++) {
      fA[f][0] = *(const short8*)(cA0 + arow + f * 1024 + kx0);
      fA[f][1] = *(const short8*)(cA0 + arow + f * 1024 + kx1);
    }
    #pragma unroll
    for (int j = 0; j < 2; j++) {
      fW1[j][0] = *(const short8*)(cW1 + brow + j * 1024 + kx0);
      fW1[j][1] = *(const short8*)(cW1 + brow + j * 1024 + kx1);
      fW2[j][0] = *(const short8*)(cW2 + brow + j * 1024 + kx0);
      fW2[j][1] = *(const short8*)(cW2 + brow + j * 1024 + kx1);
    }
    wg_barrier();   // bar1: A0/W1/W2 reads done across waves

    // region 2: stage A0,W1,W2 (u+2) -> cur; 32-MFMA cluster on A0;
    //           A1 reads issue under the MFMAs (no deps).
    if (s2) {
      glds16(gA0c0, Sb);          glds16(gA0c1, Sb + 4096);
      glds16(gW1c0, Sb + 16384);  glds16(gW1c1, Sb + 20480);
      glds16(gW2c0, Sb + 24576);  glds16(gW2c1, Sb + 28672);
    }
    __builtin_amdgcn_s_setprio(1);
    #pragma unroll
    for (int f = 0; f < 4; f++)
      #pragma unroll
      for (int j = 0; j < 2; j++) {
        acc1[f][j] = MFMA16(fA[f][0], fW1[j][0], acc1[f][j], 0, 0, 0);
        acc1[f][j] = MFMA16(fA[f][1], fW1[j][1], acc1[f][j], 0, 0, 0);
        acc2[f][j] = MFMA16(fA[f][0], fW2[j][0], acc2[f][j], 0, 0, 0);
        acc2[f][j] = MFMA16(fA[f][1], fW2[j][1], acc2[f][j], 0, 0, 0);
      }
    __builtin_amdgcn_s_setprio(0);
    #pragma unroll
    for (int f = 0; f < 4; f++) {
      fA[f][0] = *(const short8*)(cA1 + arow + f * 1024 + kx0);
      fA[f][1] = *(const short8*)(cA1 + arow + f * 1024 + kx1);
    }
    wg_barrier();   // bar2: A1 reads done across waves

    // region 3: stage A1(u+2) -> cur; 32-MFMA cluster on A1; counted vmcnt
    if (s2) { glds16(gA1c0, Sb + 8192); glds16(gA1c1, Sb + 12288); }
    gA0c0 += 64; gA0c1 += 64; gA1c0 += 64; gA1c1 += 64;
    gW1c0 += 64; gW1c1 += 64; gW2c0 += 64; gW2c1 += 64;
    __builtin_amdgcn_s_setprio(1);
    #pragma unroll
    for (int f = 0; f < 4; f++)
      #pragma unroll
      for (int j = 0; j < 2; j++) {
        acc1[4 + f][j] = MFMA16(fA[f][0], fW1[j][0], acc1[4 + f][j], 0, 0, 0);
        acc1[4 + f][j] = MFMA16(fA[f][1], fW1[j][1], acc1[4 + f][j], 0, 0, 0);
        acc2[4 + f][j] = MFMA16(fA[f][0], fW2[j][0], acc2[4 + f][j], 0, 0, 0);
        acc2[4 + f][j] = MFMA16(fA[f][1], fW2[j][1], acc2[4 + f][j], 0, 0, 0);
      }
    __builtin_amdgcn_s_setprio(0);
    if (s2)      asm volatile("s_waitcnt vmcnt(8)" ::: "memory");
    else if (s1) asm volatile("s_waitcnt vmcnt(0)" ::: "memory");
    wg_barrier();   // bar3: tile u+1 fully in LDS
  }

  #pragma unroll
  for (int f = 0; f < 8; f++) {
    int row = m0 + (f >> 2) * 128 + wm * 64 + (f & 3) * 16 + quad * 4;
    #pragma unroll
    for (int j = 0; j < 2; j++) {
      int col = n0 + wn * 32 + j * 16 + r;
      float b1 = (col < 2730) ? bias[col] : 0.f;
      float b2 = (col < 2730) ? bias[2730 + col] : 0.f;
      #pragma unroll
      for (int rr = 0; rr < 4; rr++) {
        float h1 = acc1[f][j][rr] + b1;
        float h2 = acc2[f][j][rr] + b2;
        Hb[(size_t)(row + rr) * 2816 + col] = f2bf(silu_f(h1) * h2);
      }
    }
  }
}

// ---------- MFMA flash attention, spatial: seq=256, hd=64 ----------
// 512 threads per block, both q-halves in one block; threads 0-255 prep K
// (rmsnorm+rope), 256-511 copy V transposed.
#define KSS 72
#define VSS 264
#define PSS 40
__global__ __launch_bounds__(512) void attn_s_mfma(
    const u16* __restrict__ QKV,
    const float* __restrict__ qn_w, const float* __restrict__ kn_w,
    const float* __restrict__ cosT, const float* __restrict__ sinT,
    u16* __restrict__ AO) {
  __shared__ u16 Ks[256 * KSS];
  __shared__ u16 Vt[64 * VSS];
  __shared__ u16 Pl[8 * 32 * PSS];
  int pair = blockIdx.x;
  int s = pair >> 4, h = pair & 15;
  int tid = threadIdx.x, wid = tid >> 6, lane = tid & 63;
  int quad = lane >> 4, r = lane & 15;

  if (tid < 256) {
    int j = tid;
    size_t rowb = ((size_t)(s * 256 + j)) * 3072 + (size_t)h * 64;
    const short8* kr = (const short8*)(QKV + rowb + 1024);
    float xk[64]; float ssq = 0.f;
    #pragma unroll
    for (int cg = 0; cg < 8; cg++) {
      short8 kk = kr[cg];
      #pragma unroll
      for (int e = 0; e < 8; e++) { float v = bf2f((u16)kk[e]); xk[cg * 8 + e] = v; ssq += v * v; }
    }
    float rms = rsqrtf(ssq * (1.f / 64.f) + 1e-6f);
    short8 kq[8];
    #pragma unroll
    for (int d = 0; d < 32; d++) {
      float a = xk[d] * rms * kn_w[d];
      float b2 = xk[d + 32] * rms * kn_w[d + 32];
      u16 o0 = f2bf(a * cosT[j * 64 + d] - b2 * sinT[j * 64 + d]);
      u16 o1 = f2bf(b2 * cosT[j * 64 + 32 + d] + a * sinT[j * 64 + 32 + d]);
      kq[d >> 3][d & 7] = (short)o0;
      kq[(d + 32) >> 3][d & 7] = (short)o1;
    }
    #pragma unroll
    for (int cg = 0; cg < 8; cg++) *(short8*)(Ks + j * KSS + cg * 8) = kq[cg];
  } else {
    int j = tid - 256;
    size_t rowb = ((size_t)(s * 256 + j)) * 3072 + (size_t)h * 64;
    const short8* vr = (const short8*)(QKV + rowb + 2048);
    #pragma unroll
    for (int cg = 0; cg < 8; cg++) {
      short8 vv = vr[cg];
      #pragma unroll
      for (int e = 0; e < 8; e++) Vt[(cg * 8 + e) * VSS + j] = (u16)vv[e];
    }
  }

  int qbase = wid * 32;   // 8 waves cover 256 q rows
  short8 qa[2][2];
  float lrow[2][4];
  {
    float qv[2][2][8];
    float ssq[2] = {0.f, 0.f};
    #pragma unroll
    for (int i = 0; i < 2; i++) {
      int grow = s * 256 + qbase + i * 16 + r;
      #pragma unroll
      for (int kk = 0; kk < 2; kk++) {
        short8 qraw = *(const short8*)(QKV + (size_t)grow * 3072 + h * 64 + kk * 32 + quad * 8);
        #pragma unroll
        for (int e = 0; e < 8; e++) { float v = bf2f((u16)qraw[e]); qv[i][kk][e] = v; ssq[i] += v * v; }
      }
    }
    #pragma unroll
    for (int i = 0; i < 2; i++) {
      float sv = ssq[i];
      sv += __shfl_xor(sv, 16);
      sv += __shfl_xor(sv, 32);
      float rms = rsqrtf(sv * (1.f / 64.f) + 1e-6f);
      int qrow = qbase + i * 16 + r;
      #pragma unroll
      for (int e = 0; e < 8; e++) {
        int d0 = quad * 8 + e;
        float a = qv[i][0][e] * rms * qn_w[d0];
        float b2 = qv[i][1][e] * rms * qn_w[d0 + 32];
        qa[i][0][e] = (short)f2bf(a * cosT[qrow * 64 + d0] - b2 * sinT[qrow * 64 + d0]);
        qa[i][1][e] = (short)f2bf(b2 * cosT[qrow * 64 + 32 + d0] + a * sinT[qrow * 64 + 32 + d0]);
      }
    }
  }
  __syncthreads();

  f32x4 zero = {0.f, 0.f, 0.f, 0.f};
  f32x4 acc[2][16];
  #pragma unroll
  for (int i = 0; i < 2; i++)
    #pragma unroll
    for (int j = 0; j < 16; j++) acc[i][j] = zero;
  #pragma unroll
  for (int kk = 0; kk < 2; kk++) {
    #pragma unroll
    for (int j = 0; j < 16; j++) {
      short8 bfr = *(const short8*)(Ks + (j * 16 + r) * KSS + kk * 32 + quad * 8);
      acc[0][j] = MFMA16(qa[0][kk], bfr, acc[0][j], 0, 0, 0);
      acc[1][j] = MFMA16(qa[1][kk], bfr, acc[1][j], 0, 0, 0);
    }
  }

  #pragma unroll
  for (int i = 0; i < 2; i++) {
    #pragma unroll
    for (int rr = 0; rr < 4; rr++) {
      float mx = acc[i][0][rr];
      #pragma unroll
      for (int j = 1; j < 16; j++) mx = fmaxf(mx, acc[i][j][rr]);
      #pragma unroll
      for (int msk = 1; msk < 16; msk <<= 1) mx = fmaxf(mx, __shfl_xor(mx, msk));
      float ls = 0.f;
      #pragma unroll
      for (int j = 0; j < 16; j++) { float p = __expf((acc[i][j][rr] - mx) * 0.125f); acc[i][j][rr] = p; ls += p; }
      #pragma unroll
      for (int msk = 1; msk < 16; msk <<= 1) ls += __shfl_xor(ls, msk);
      lrow[i][rr] = ls;
    }
  }

  f32x4 oacc[2][4];
  #pragma unroll
  for (int i = 0; i < 2; i++)
    #pragma unroll
    for (int j = 0; j < 4; j++) oacc[i][j] = zero;
  u16* plw = Pl + wid * 32 * PSS;
  #pragma unroll
  for (int kk = 0; kk < 8; kk++) {
    #pragma unroll
    for (int i = 0; i < 2; i++)
      #pragma unroll
      for (int jj = 0; jj < 2; jj++) {
        int j = kk * 2 + jj;
        #pragma unroll
        for (int rr = 0; rr < 4; rr++)
          plw[(i * 16 + quad * 4 + rr) * PSS + jj * 16 + r] = f2bf(acc[i][j][rr]);
      }
    short8 pa0 = *(const short8*)(plw + r * PSS + quad * 8);
    short8 pa1 = *(const short8*)(plw + (16 + r) * PSS + quad * 8);
    #pragma unroll
    for (int j4 = 0; j4 < 4; j4++) {
      short8 vfr = *(const short8*)(Vt + (j4 * 16 + r) * VSS + kk * 32 + quad * 8);
      oacc[0][j4] = MFMA16(pa0, vfr, oacc[0][j4], 0, 0, 0);
      oacc[1][j4] = MFMA16(pa1, vfr, oacc[1][j4], 0, 0, 0);
    }
  }

  #pragma unroll
  for (int i = 0; i < 2; i++) {
    #pragma unroll
    for (int rr = 0; rr < 4; rr++) {
      float inv = 1.f / lrow[i][rr];
      int row = s * 256 + qbase + i * 16 + quad * 4 + rr;
      #pragma unroll
      for (int j4 = 0; j4 < 4; j4++)
        AO[(size_t)row * 1024 + h * 64 + j4 * 16 + r] = f2bf(oacc[i][j4][rr] * inv);
    }
  }
}

// ---------- temporal attention: seq=16, block per (b,l), thread = (head, t) ----------
__global__ __launch_bounds__(256) void attn_t_kernel(
    const u16* __restrict__ QKV,
    const float* __restrict__ qn_w, const float* __restrict__ kn_w,
    const float* __restrict__ cosT, const float* __restrict__ sinT,
    u16* __restrict__ AO) {
  __shared__ u16 kb[256 * 64];
  __shared__ u16 vb[256 * 64];
  int bl = blockIdx.x;
  int tid = threadIdx.x;
  int h = tid >> 4, t = tid & 15;
  size_t rowbase = ((size_t)(bl * 16 + t)) * 3072;
  int slot = h * 16 + t;
  {
    const u16* kr = QKV + rowbase + 1024 + h * 64;
    float xk[64]; float ss = 0.f;
    #pragma unroll
    for (int d = 0; d < 64; d++) { xk[d] = bf2f(kr[d]); ss += xk[d] * xk[d]; }
    float rms = rsqrtf(ss * (1.f / 64.f) + 1e-6f);
    #pragma unroll
    for (int d = 0; d < 64; d++) xk[d] *= rms * kn_w[d];
    #pragma unroll
    for (int d = 0; d < 32; d++) {
      float a = xk[d], bb = xk[d + 32];
      kb[slot * 64 + d]      = f2bf(a * cosT[t * 64 + d]       - bb * sinT[t * 64 + d]);
      kb[slot * 64 + 32 + d] = f2bf(bb * cosT[t * 64 + 32 + d] + a * sinT[t * 64 + 32 + d]);
    }
    const u16* vr = QKV + rowbase + 2048 + h * 64;
    #pragma unroll
    for (int d = 0; d < 64; d++) vb[slot * 64 + d] = vr[d];
  }
  float q[64];
  {
    const u16* qr = QKV + rowbase + h * 64;
    float ss = 0.f;
    #pragma unroll
    for (int d = 0; d < 64; d++) { q[d] = bf2f(qr[d]); ss += q[d] * q[d]; }
    float rms = rsqrtf(ss * (1.f / 64.f) + 1e-6f);
    #pragma unroll
    for (int d = 0; d < 64; d++) q[d] *= rms * qn_w[d];
    #pragma unroll
    for (int d = 0; d < 32; d++) {
      float a = q[d], bb = q[d + 32];
      q[d]      = a * cosT[t * 64 + d]       - bb * sinT[t * 64 + d];
      q[d + 32] = bb * cosT[t * 64 + 32 + d] + a * sinT[t * 64 + 32 + d];
    }
  }
  __syncthreads();
  float scv[16]; float mx = -1e30f;
  #pragma unroll
  for (int j = 0; j < 16; j++) {
    float sc = 0.f;
    const short8* krow = (const short8*)(kb + (h * 16 + j) * 64);
    #pragma unroll
    for (int vv = 0; vv < 8; vv++) {
      short8 kk = krow[vv];
      #pragma unroll
      for (int e = 0; e < 8; e++) sc += q[vv * 8 + e] * bf2f((u16)kk[e]);
    }
    scv[j] = sc * 0.125f;
    mx = fmaxf(mx, scv[j]);
  }
  float ssum = 0.f;
  #pragma unroll
  for (int j = 0; j < 16; j++) { scv[j] = __expf(scv[j] - mx); ssum += scv[j]; }
  float inv = 1.f / ssum;
  float o[64];
  #pragma unroll
  for (int d = 0; d < 64; d++) o[d] = 0.f;
  #pragma unroll
  for (int j = 0; j < 16; j++) {
    const short8* vrow = (const short8*)(vb + (h * 16 + j) * 64);
    #pragma unroll
    for (int vv = 0; vv < 8; vv++) {
      short8 vk = vrow[vv];
      #pragma unroll
      for (int e = 0; e < 8; e++) o[vv * 8 + e] += scv[j] * bf2f((u16)vk[e]);
    }
  }
  u16* op = AO + ((size_t)(bl * 16 + t)) * 1024 + h * 64;
  #pragma unroll
  for (int d = 0; d < 64; d++) op[d] = f2bf(o[d] * inv);
}

// =====================================================================
extern "C" void kernel_launch(void* const* d_in, const int* in_sizes, int n_in,
                              void* d_out, int out_size, void* d_ws, size_t ws_size,
                              hipStream_t stream) {
  const float* x        = (const float*)d_in[0];
  const float* c        = (const float*)d_in[1];
  const float* cos_s    = (const float*)d_in[2];
  const float* sin_s    = (const float*)d_in[3];
  const float* cos_t    = (const float*)d_in[4];
  const float* sin_t    = (const float*)d_in[5];
  const float* norm1w   = (const float*)d_in[6];
  const float* norm2w   = (const float*)d_in[7];
  const float* norm3w   = (const float*)d_in[8];
  const float* qkv_s_w  = (const float*)d_in[9];
  const float* qkv_s_b  = (const float*)d_in[10];
  const float* qn_s_w   = (const float*)d_in[11];
  const float* kn_s_w   = (const float*)d_in[12];
  const float* proj_s_w = (const float*)d_in[13];
  const float* proj_s_b = (const float*)d_in[14];
  const float* qkv_t_w  = (const float*)d_in[15];
  const float* qkv_t_b  = (const float*)d_in[16];
  const float* qn_t_w   = (const float*)d_in[17];
  const float* kn_t_w   = (const float*)d_in[18];
  const float* proj_t_w = (const float*)d_in[19];
  const float* proj_t_b = (const float*)d_in[20];
  const float* w12_w    = (const float*)d_in[21];
  const float* w12_b    = (const float*)d_in[22];
  const float* w3_w     = (const float*)d_in[23];
  const float* w3_b     = (const float*)d_in[24];
  const float* ada_w    = (const float*)d_in[25];
  const float* ada_b    = (const float*)d_in[26];
  float* out = (float*)d_out;

  // ---- workspace layout (unchanged) ----
  char* wsp = (char*)d_ws;
  size_t off = 0;
  auto alloc = [&](size_t bytes) { size_t p = off; off += (bytes + 255) & ~(size_t)255; return p; };
  float* modsb = (float*)(wsp + alloc(2 * 9216 * 4));
  u16*   BIG   = (u16*)  (wsp + alloc((size_t)8192 * 3072 * 2));  // QKV (st1,2) / Hb 8192x2816 (st3)
  char*  XnP   = (char*) (wsp + alloc((size_t)8192 * 1024 * 4));  // Xn bf16
  u16*   AO    = (u16*)  (wsp + alloc((size_t)8192 * 1024 * 2));
  u16*   Wq    = (u16*)  (wsp + alloc((size_t)3072 * 1024 * 2));
  u16*   Wp    = (u16*)  (wsp + alloc((size_t)2816 * 1024 * 2));
  u16*   W3b   = (u16*)  (wsp + alloc((size_t)1024 * 2816 * 2));
  u16* W1p = Wq;
  u16* W2p = Wp;
  u16* Xn  = (u16*)XnP;
  float* Xcur = out;   // residual stream lives in d_out

  dim3 blk(256);
  dim3 blk512(512);
  mods_kernel<<<2304, blk, 0, stream>>>(c, ada_w, ada_b, modsb);

  // ---- stage 1: spatial attention ----
  {
    int n0 = 3072 * 1024, n1 = 1024 * 1024;
    cvt2_kernel<<<(n0 + n1) / 1024, blk, 0, stream>>>(qkv_s_w, Wq, n0, proj_s_w, Wp, n1);
  }
  norm_mod_kernel<<<8192, blk, 0, stream>>>(x, Xn, norm1w, modsb, 0, 0);
  // QKV: BK=32 2-blocks/CU kernel; grid 32x24 = 768
  gemm256_qkv<<<dim3(32 * 24), blk512, 0, stream>>>(Xn, Wq, qkv_s_b, BIG, 1024, 3072);
  attn_s_mfma<<<dim3(512), blk512, 0, stream>>>(BIG, qn_s_w, kn_s_w, cos_s, sin_s, AO);
  // proj + residual fused: Xcur = x + g2 * (AO @ Wp^T + b)
  gemm256_n128<2><<<dim3(32 * 8), blk512, 0, stream>>>(AO, Wp, proj_s_b, Xcur, 1024, 1024, x, modsb, 2);

  // ---- stage 2: temporal attention (rows in (b,l,t) order) ----
  {
    int n0 = 3072 * 1024, n1 = 1024 * 1024;
    cvt2_kernel<<<(n0 + n1) / 1024, blk, 0, stream>>>(qkv_t_w, Wq, n0, proj_t_w, Wp, n1);
  }
  norm_mod_kernel<<<8192, blk, 0, stream>>>(Xcur, Xn, norm2w, modsb, 3, 1);
  gemm256_qkv<<<dim3(32 * 24), blk512, 0, stream>>>(Xn, Wq, qkv_t_b, BIG, 1024, 3072);
  attn_t_kernel<<<512, blk, 0, stream>>>(BIG, qn_t_w, kn_t_w, cos_t, sin_t, AO);
  // proj + residual fused with (b,l,t)->(b,t,l) transpose: Xcur = Xcur + g5 * T(proj)
  gemm256_n128<3><<<dim3(32 * 8), blk512, 0, stream>>>(AO, Wp, proj_t_b, Xcur, 1024, 1024, Xcur, modsb, 5);

  // ---- stage 3: SwiGLU MLP (HFF 2730 padded to 2816) ----
  {
    int tot = 2 * 2816 * 1024 + 1024 * 2816;
    cvt3_kernel<<<(tot + 255) / 256, blk, 0, stream>>>(w12_w, W1p, W2p, w3_w, W3b);
  }
  norm_mod_kernel<<<8192, blk, 0, stream>>>(Xcur, Xn, norm3w, modsb, 6, 0);
  gemm256_w12<<<dim3(32 * 22), blk512, 0, stream>>>(Xn, W1p, W2p, w12_b, BIG);
  // w3 + residual fused: out = Xcur + g8 * (Hb @ W3^T + b)
  gemm256_n128<2><<<dim3(32 * 8), blk512, 0, stream>>>(BIG, W3b, w3_b, out, 2816, 1024, Xcur, modsb, 8);
}

// Round 9
// 641.326 us; speedup vs baseline: 1.1709x; 1.0533x over previous
//
#include <hip/hip_runtime.h>
#include <cstdint>
#include <cstddef>

typedef unsigned short u16;
typedef __attribute__((ext_vector_type(8))) short short8;
typedef __attribute__((ext_vector_type(4))) float f32x4;

// ---------- bf16 helpers (OCP bf16 = top 16 bits of fp32, RNE) ----------
__device__ __forceinline__ float bf2f(u16 u) {
  union { uint32_t u; float f; } x; x.u = ((uint32_t)u) << 16; return x.f;
}
__device__ __forceinline__ u16 f2bf(float f) {
  union { float f; uint32_t u; } x; x.f = f;
  uint32_t r = x.u + 0x7FFFu + ((x.u >> 16) & 1u);
  return (u16)(r >> 16);
}
__device__ __forceinline__ float silu_f(float x) { return x / (1.f + __expf(-x)); }

// async global->LDS, 16 B per lane; LDS dst = wave-uniform base + lane*16
__device__ __forceinline__ void glds16(const u16* g, u16* l) {
  __builtin_amdgcn_global_load_lds(
      (const __attribute__((address_space(1))) void*)g,
      (__attribute__((address_space(3))) void*)l, 16, 0, 0);
}

#define MFMA16 __builtin_amdgcn_mfma_f32_16x16x32_bf16

// raw barrier with compiler memory fences only.
__device__ __forceinline__ void wg_barrier() {
  asm volatile("" ::: "memory");
  __builtin_amdgcn_s_barrier();
  asm volatile("" ::: "memory");
}

// ---------- merged weight conversions ----------
__global__ void cvt2_kernel(const float* __restrict__ in0, u16* __restrict__ out0, int n0,
                            const float* __restrict__ in1, u16* __restrict__ out1, int n1) {
  int i = (blockIdx.x * 256 + threadIdx.x) * 4;
  const float* in; u16* out;
  if (i < n0) { in = in0 + i; out = out0 + i; }
  else { i -= n0; if (i >= n1) return; in = in1 + i; out = out1 + i; }
  float4 v = *(const float4*)in;
  ushort4 o; o.x = f2bf(v.x); o.y = f2bf(v.y); o.z = f2bf(v.z); o.w = f2bf(v.w);
  *(ushort4*)out = o;
}

__global__ void cvt3_kernel(const float* __restrict__ w12, u16* __restrict__ W1, u16* __restrict__ W2,
                            const float* __restrict__ w3, u16* __restrict__ W3) {
  int i = blockIdx.x * 256 + threadIdx.x;
  const int n1 = 2816 * 1024;
  const int n3 = 1024 * 2816;
  if (i < n1) {
    int r = i >> 10, c = i & 1023;
    W1[i] = f2bf(r < 2730 ? w12[(size_t)r * 1024 + c] : 0.f);
  } else if (i < 2 * n1) {
    int j = i - n1; int r = j >> 10, c = j & 1023;
    W2[j] = f2bf(r < 2730 ? w12[(size_t)(r + 2730) * 1024 + c] : 0.f);
  } else {
    int j = i - 2 * n1; if (j >= n3) return;
    int r = j / 2816, c = j - r * 2816;
    W3[j] = f2bf(c < 2730 ? w3[(size_t)r * 2730 + c] : 0.f);
  }
}

// ---------- mods = silu(c) @ ada_w.T + ada_b ----------
__global__ void mods_kernel(const float* __restrict__ c, const float* __restrict__ ada_w,
                            const float* __restrict__ ada_b, float* __restrict__ mods) {
  int j = blockIdx.x * 4 + (threadIdx.x >> 6);
  int lane = threadIdx.x & 63;
  float a0 = 0.f, a1 = 0.f;
  for (int k = lane; k < 1024; k += 64) {
    float w = ada_w[(size_t)j * 1024 + k];
    a0 += silu_f(c[k]) * w;
    a1 += silu_f(c[1024 + k]) * w;
  }
  #pragma unroll
  for (int off = 32; off > 0; off >>= 1) { a0 += __shfl_down(a0, off); a1 += __shfl_down(a1, off); }
  if (lane == 0) {
    float bb = ada_b[j];
    mods[j] = a0 + bb;
    mods[9216 + j] = a1 + bb;
  }
}

// ---------- rmsnorm(D=1024) * (1+sc) + sh  -> bf16 rows; optional (t,l) transpose ----------
__global__ __launch_bounds__(256) void norm_mod_kernel(
    const float* __restrict__ X, u16* __restrict__ Y,
    const float* __restrict__ nw, const float* __restrict__ mods,
    int sh_idx, int transpose) {
  int row = blockIdx.x;
  int b = row >> 12;
  int in_row;
  if (transpose) { int rem = row & 4095; int l = rem >> 4, t = rem & 15; in_row = (b << 12) + (t << 8) + l; }
  else in_row = row;
  int tid = threadIdx.x;
  float4 v = ((const float4*)(X + (size_t)in_row * 1024))[tid];
  float ss = v.x * v.x + v.y * v.y + v.z * v.z + v.w * v.w;
  #pragma unroll
  for (int off = 32; off > 0; off >>= 1) ss += __shfl_down(ss, off);
  __shared__ float red[4];
  if ((tid & 63) == 0) red[tid >> 6] = ss;
  __syncthreads();
  float rms = rsqrtf((red[0] + red[1] + red[2] + red[3]) * (1.f / 1024.f) + 1e-6f);
  const float* mb = mods + (size_t)b * 9216 + (size_t)sh_idx * 1024;
  float4 sh = ((const float4*)mb)[tid];
  float4 sc = ((const float4*)(mb + 1024))[tid];
  float4 w  = ((const float4*)nw)[tid];
  ushort4 o;
  o.x = f2bf(v.x * rms * w.x * (1.f + sc.x) + sh.x);
  o.y = f2bf(v.y * rms * w.y * (1.f + sc.y) + sh.y);
  o.z = f2bf(v.z * rms * w.z * (1.f + sc.z) + sh.z);
  o.w = f2bf(v.w * rms * w.w * (1.f + sc.w) + sh.w);
  ((ushort4*)(Y + (size_t)row * 1024))[tid] = o;
}

// =====================================================================
// 256-tile GEMM machinery.
// LDS slot = 16KB: row-major [128][64] bf16, col ^= (row&7)<<3 bank swizzle.
// glds writes linearly; swizzle applied by pre-swizzling the GLOBAL source col.
//
// Round-9 gemm256_n128: REGISTER-PIPELINED FRAGMENTS. Every prior variant
// read a tile's fragments and MFMA'd them in the same region, so the
// compiler's lgkmcnt wait before the first MFMA serialized the LDS pipe
// (~1170 cyc/CU/K-tile) against the matrix pipe (~1240 cyc). Now two frag
// register sets ping-pong (2-body unrolled loop, static indices): body for
// tile u computes on SET-X (read one body earlier) while SET-Y's ds_reads
// for tile u+1 and the glds staging of tile u+2 fly underneath. lgkmcnt(0)
// and vmcnt(0) land AFTER the MFMA cluster.
// Restage safety: buffer B's reads are lgkm-drained + barrier-sealed in the
// body before B is restaged.
// =====================================================================
#define CHK2(b, s) (((b) * 4 + (s)) << 13)
#define CHK3(b, s) (((b) * 3 + (s)) << 13)

__device__ __forceinline__ void stage_half(const u16* __restrict__ gp, int ldk,
                                           int row_base, int k0,
                                           u16* Sbase, int slot_u16,
                                           int wid, int srow, int scol) {
  #pragma unroll
  for (int c = 0; c < 2; c++) {
    int row = c * 64 + wid * 8 + srow;
    glds16(gp + (size_t)(row_base + row) * ldk + (k0 + scol),
           Sbase + slot_u16 + c * 4096 + wid * 512);
  }
}

// ---------- dense 256x128-tile GEMM, register-pipelined, fused epilogues ----------
// MODE 0: fp32 C; MODE 1: bf16 C; MODE 2: out = base + g*(acc+bias) fp32;
// MODE 3: MODE 2 with (b,l,t)->(b,t,l) row transpose.
// 512 threads, 8 waves as 4m x 2n -> per-wave 64x64 output (16 reads / 32 MFMA).
// grid = 32 * (N/128); LDS = 2 buf x 3 slots x 16KB = 96 KB. K/64 must be EVEN.
template<int MODE>
__global__ __launch_bounds__(512, 2) void gemm256_n128(
    const u16* __restrict__ A, const u16* __restrict__ W,
    const float* __restrict__ bias, void* __restrict__ Cv,
    int K, int ldc,
    const float* __restrict__ base, const float* __restrict__ mods, int gidx) {
  __shared__ u16 S[49152];   // 96 KB
  const int tid = threadIdx.x, wid = tid >> 6, lane = tid & 63;
  const int wm = wid >> 1, wn = wid & 1;        // 4m x 2n wave grid
  const int quad = lane >> 4, r = lane & 15;
  const int bid = blockIdx.x, xcd = bid & 7, l = bid >> 3;
  const int mt = (xcd << 2) | (l & 3), nt = l >> 2;
  const int m0 = mt * 256, n0 = nt * 128;

  const int srow = lane >> 3;
  const int scol = ((lane & 7) ^ srow) << 3;
  const int kx0 = (quad * 8) ^ ((r & 7) << 3);
  const int kx1 = (32 + quad * 8) ^ ((r & 7) << 3);
  const int aslot = wm >> 1;                    // which A slot this wave reads
  const int arow = ((wm & 1) * 64 + r) * 64;    // + f*16*64
  const int brow = (wn * 64 + r) * 64;          // + j*16*64

  f32x4 zero = {0.f, 0.f, 0.f, 0.f};
  f32x4 acc[4][4];
  #pragma unroll
  for (int i = 0; i < 4; i++)
    #pragma unroll
    for (int j = 0; j < 4; j++) acc[i][j] = zero;
  // two register fragment sets (ping-pong; all indices static)
  short8 fAa[4][2], fBa[4][2], fAb[4][2], fBb[4][2];

  const int nk = K >> 6;   // must be even

  // hoisted staging pointers: first staged tile is tile 2 (k=128); +64/tile
  const u16* gA0c0 = A + (size_t)(m0 +       wid * 8 + srow) * K + scol + 128;
  const u16* gA0c1 = A + (size_t)(m0 +  64 + wid * 8 + srow) * K + scol + 128;
  const u16* gA1c0 = A + (size_t)(m0 + 128 + wid * 8 + srow) * K + scol + 128;
  const u16* gA1c1 = A + (size_t)(m0 + 192 + wid * 8 + srow) * K + scol + 128;
  const u16* gBc0  = W + (size_t)(n0 +       wid * 8 + srow) * K + scol + 128;
  const u16* gBc1  = W + (size_t)(n0 +  64 + wid * 8 + srow) * K + scol + 128;

  // prologue: tile0 -> buf0, tile1 -> buf1
  stage_half(A, K, m0,       0, S, CHK3(0,0), wid, srow, scol);
  stage_half(A, K, m0 + 128, 0, S, CHK3(0,1), wid, srow, scol);
  stage_half(W, K, n0,       0, S, CHK3(0,2), wid, srow, scol);
  stage_half(A, K, m0,       64, S, CHK3(1,0), wid, srow, scol);
  stage_half(A, K, m0 + 128, 64, S, CHK3(1,1), wid, srow, scol);
  stage_half(W, K, n0,       64, S, CHK3(1,2), wid, srow, scol);
  asm volatile("s_waitcnt vmcnt(0)" ::: "memory");
  __builtin_amdgcn_s_barrier();

  // read tile0 fragments into SET A
  {
    const u16* cA = S + CHK3(0, aslot);
    const u16* cB = S + CHK3(0, 2);
    #pragma unroll
    for (int f = 0; f < 4; f++) {
      fAa[f][0] = *(const short8*)(cA + arow + f * 1024 + kx0);
      fAa[f][1] = *(const short8*)(cA + arow + f * 1024 + kx1);
    }
    #pragma unroll
    for (int j = 0; j < 4; j++) {
      fBa[j][0] = *(const short8*)(cB + brow + j * 1024 + kx0);
      fBa[j][1] = *(const short8*)(cB + brow + j * 1024 + kx1);
    }
  }
  asm volatile("s_waitcnt lgkmcnt(0)" ::: "memory");
  __builtin_amdgcn_s_barrier();   // all waves' tile-0 reads done -> buf0 restageable

  for (int u2 = 0; u2 < nk; u2 += 2) {
    const int s2a = (u2 + 2 < nk);
    // ---- even body: compute tile u2 (SET A, buf0); read tile u2+1 -> SET B; stage u2+2 -> buf0
    if (s2a) {
      u16* Sb = S + wid * 512;   // buf0
      glds16(gA0c0, Sb);          glds16(gA0c1, Sb + 4096);
      glds16(gA1c0, Sb + 8192);   glds16(gA1c1, Sb + 12288);
      glds16(gBc0,  Sb + 16384);  glds16(gBc1,  Sb + 20480);
      gA0c0 += 64; gA0c1 += 64; gA1c0 += 64; gA1c1 += 64; gBc0 += 64; gBc1 += 64;
    }
    {
      const u16* cA = S + CHK3(1, aslot);
      const u16* cB = S + CHK3(1, 2);
      #pragma unroll
      for (int f = 0; f < 4; f++) {
        fAb[f][0] = *(const short8*)(cA + arow + f * 1024 + kx0);
        fAb[f][1] = *(const short8*)(cA + arow + f * 1024 + kx1);
      }
      #pragma unroll
      for (int j = 0; j < 4; j++) {
        fBb[j][0] = *(const short8*)(cB + brow + j * 1024 + kx0);
        fBb[j][1] = *(const short8*)(cB + brow + j * 1024 + kx1);
      }
    }
    __builtin_amdgcn_s_setprio(1);
    #pragma unroll
    for (int f = 0; f < 4; f++)
      #pragma unroll
      for (int j = 0; j < 4; j++) {
        acc[f][j] = MFMA16(fAa[f][0], fBa[j][0], acc[f][j], 0, 0, 0);
        acc[f][j] = MFMA16(fAa[f][1], fBa[j][1], acc[f][j], 0, 0, 0);
      }
    __builtin_amdgcn_s_setprio(0);
    asm volatile("s_waitcnt lgkmcnt(0)" ::: "memory");   // SET B landed
    if (s2a) asm volatile("s_waitcnt vmcnt(0)" ::: "memory"); // tile u2+2 in buf0
    __builtin_amdgcn_s_barrier();

    // ---- odd body: compute tile u2+1 (SET B, buf1); read tile u2+2 -> SET A; stage u2+3 -> buf1
    const int s2b = (u2 + 3 < nk);
    if (s2b) {
      u16* Sb = S + 24576 + wid * 512;   // buf1
      glds16(gA0c0, Sb);          glds16(gA0c1, Sb + 4096);
      glds16(gA1c0, Sb + 8192);   glds16(gA1c1, Sb + 12288);
      glds16(gBc0,  Sb + 16384);  glds16(gBc1,  Sb + 20480);
      gA0c0 += 64; gA0c1 += 64; gA1c0 += 64; gA1c1 += 64; gBc0 += 64; gBc1 += 64;
    }
    if (s2a) {
      const u16* cA = S + CHK3(0, aslot);
      const u16* cB = S + CHK3(0, 2);
      #pragma unroll
      for (int f = 0; f < 4; f++) {
        fAa[f][0] = *(const short8*)(cA + arow + f * 1024 + kx0);
        fAa[f][1] = *(const short8*)(cA + arow + f * 1024 + kx1);
      }
      #pragma unroll
      for (int j = 0; j < 4; j++) {
        fBa[j][0] = *(const short8*)(cB + brow + j * 1024 + kx0);
        fBa[j][1] = *(const short8*)(cB + brow + j * 1024 + kx1);
      }
    }
    __builtin_amdgcn_s_setprio(1);
    #pragma unroll
    for (int f = 0; f < 4; f++)
      #pragma unroll
      for (int j = 0; j < 4; j++) {
        acc[f][j] = MFMA16(fAb[f][0], fBb[j][0], acc[f][j], 0, 0, 0);
        acc[f][j] = MFMA16(fAb[f][1], fBb[j][1], acc[f][j], 0, 0, 0);
      }
    __builtin_amdgcn_s_setprio(0);
    if (s2a) asm volatile("s_waitcnt lgkmcnt(0)" ::: "memory");  // SET A landed
    if (s2b) asm volatile("s_waitcnt vmcnt(0)" ::: "memory");    // tile u2+3 in buf1
    __builtin_amdgcn_s_barrier();
  }

  float* Cf = (float*)Cv;
  u16* Ch = (u16*)Cv;
  #pragma unroll
  for (int f = 0; f < 4; f++) {
    int row = m0 + wm * 64 + f * 16 + quad * 4;
    #pragma unroll
    for (int j = 0; j < 4; j++) {
      int col = n0 + wn * 64 + j * 16 + r;
      float bv = bias[col];
      #pragma unroll
      for (int rr = 0; rr < 4; rr++) {
        int ri = row + rr;
        float vv = acc[f][j][rr] + bv;
        if (MODE == 0) {
          Cf[(size_t)ri * ldc + col] = vv;
        } else if (MODE == 1) {
          Ch[(size_t)ri * ldc + col] = f2bf(vv);
        } else {
          int ro = ri;
          if (MODE == 3) { int rem = ri & 4095; ro = (ri & ~4095) + ((rem & 15) << 8) + (rem >> 4); }
          int b = ri >> 12;
          float g = mods[(size_t)b * 9216 + (size_t)gidx * 1024 + col];
          Cf[(size_t)ro * 1024 + col] = base[(size_t)ro * 1024 + col] + g * vv;
        }
      }
    }
  }
}

// ---------- fused w12 + SwiGLU, 256x128 tile, 3 barriers/K-tile (r6 proven) ----------
// 8 waves 2m x 4n; per-wave 128 rows x 32 cols for BOTH GEMMs (acc1, acc2).
// LDS: 2 buf x 4 slots (A0, A1, W1, W2) x 16KB = 128 KB.
__global__ __launch_bounds__(512, 2) void gemm256_w12(
    const u16* __restrict__ A, const u16* __restrict__ W1, const u16* __restrict__ W2,
    const float* __restrict__ bias, u16* __restrict__ Hb) {
  __shared__ u16 S[65536];
  const int tid = threadIdx.x, wid = tid >> 6, lane = tid & 63;
  const int wm = wid >> 2, wn = wid & 3;
  const int quad = lane >> 4, r = lane & 15;
  const int bid = blockIdx.x, xcd = bid & 7, l = bid >> 3;
  const int mt = (xcd << 2) | (l & 3), nt = l >> 2;   // nt in [0,22)
  const int m0 = mt * 256, n0 = nt * 128;

  const int srow = lane >> 3;
  const int scol = ((lane & 7) ^ srow) << 3;
  const int kx0 = (quad * 8) ^ ((r & 7) << 3);
  const int kx1 = (32 + quad * 8) ^ ((r & 7) << 3);
  const int arow = (wm * 64 + r) * 64;
  const int brow = (wn * 32 + r) * 64;
  const int K = 1024, nk = 16;

  f32x4 zero = {0.f, 0.f, 0.f, 0.f};
  f32x4 acc1[8][2], acc2[8][2];
  #pragma unroll
  for (int i = 0; i < 8; i++)
    #pragma unroll
    for (int j = 0; j < 2; j++) { acc1[i][j] = zero; acc2[i][j] = zero; }
  short8 fA[4][2], fW1[2][2], fW2[2][2];

  // hoisted staging pointers (k starts at 128 = tile u+2 for u=0)
  const u16* gA0c0 = A  + (size_t)(m0 +       wid * 8 + srow) * K + scol + 128;
  const u16* gA0c1 = A  + (size_t)(m0 +  64 + wid * 8 + srow) * K + scol + 128;
  const u16* gA1c0 = A  + (size_t)(m0 + 128 + wid * 8 + srow) * K + scol + 128;
  const u16* gA1c1 = A  + (size_t)(m0 + 192 + wid * 8 + srow) * K + scol + 128;
  const u16* gW1c0 = W1 + (size_t)(n0 +       wid * 8 + srow) * K + scol + 128;
  const u16* gW1c1 = W1 + (size_t)(n0 +  64 + wid * 8 + srow) * K + scol + 128;
  const u16* gW2c0 = W2 + (size_t)(n0 +       wid * 8 + srow) * K + scol + 128;
  const u16* gW2c1 = W2 + (size_t)(n0 +  64 + wid * 8 + srow) * K + scol + 128;

  // prologue: tile0 then tile1
  stage_half(A,  K, m0,       0, S, CHK2(0,0), wid, srow, scol);
  stage_half(W1, K, n0,       0, S, CHK2(0,2), wid, srow, scol);
  stage_half(W2, K, n0,       0, S, CHK2(0,3), wid, srow, scol);
  stage_half(A,  K, m0 + 128, 0, S, CHK2(0,1), wid, srow, scol);
  stage_half(A,  K, m0,      64, S, CHK2(1,0), wid, srow, scol);
  stage_half(W1, K, n0,      64, S, CHK2(1,2), wid, srow, scol);
  stage_half(W2, K, n0,      64, S, CHK2(1,3), wid, srow, scol);
  stage_half(A,  K, m0 + 128,64, S, CHK2(1,1), wid, srow, scol);
  asm volatile("s_waitcnt vmcnt(8)" ::: "memory");
  __builtin_amdgcn_s_barrier();

  for (int u = 0; u < nk; ++u) {
    const int cur = u & 1;
    const int s1 = (u + 1 < nk), s2 = (u + 2 < nk);
    const u16* cA0 = S + CHK2(cur, 0);
    const u16* cA1 = S + CHK2(cur, 1);
    const u16* cW1 = S + CHK2(cur, 2);
    const u16* cW2 = S + CHK2(cur, 3);
    u16* Sb = S + cur * 32768 + wid * 512;   // restage base (slots at +0/8192/16384/24576)

    // region 1: read A0 + W1 + W2
    #pragma unroll
    for (int f = 0; f < 4; f++) {
      fA[f][0] = *(const short8*)(cA0 + arow + f * 1024 + kx0);
      fA[f][1] = *(const short8*)(cA0 + arow + f * 1024 + kx1);
    }
    #pragma unroll
    for (int j = 0; j < 2; j++) {
      fW1[j][0] = *(const short8*)(cW1 + brow + j * 1024 + kx0);
      fW1[j][1] = *(const short8*)(cW1 + brow + j * 1024 + kx1);
      fW2[j][0] = *(const short8*)(cW2 + brow + j * 1024 + kx0);
      fW2[j][1] = *(const short8*)(cW2 + brow + j * 1024 + kx1);
    }
    wg_barrier();   // bar1: A0/W1/W2 reads done across waves

    // region 2: stage A0,W1,W2 (u+2) -> cur; 32-MFMA cluster on A0;
    //           A1 reads issue under the MFMAs (no deps).
    if (s2) {
      glds16(gA0c0, Sb);          glds16(gA0c1, Sb + 4096);
      glds16(gW1c0, Sb + 16384);  glds16(gW1c1, Sb + 20480);
      glds16(gW2c0, Sb + 24576);  glds16(gW2c1, Sb + 28672);
    }
    __builtin_amdgcn_s_setprio(1);
    #pragma unroll
    for (int f = 0; f < 4; f++)
      #pragma unroll
      for (int j = 0; j < 2; j++) {
        acc1[f][j] = MFMA16(fA[f][0], fW1[j][0], acc1[f][j], 0, 0, 0);
        acc1[f][j] = MFMA16(fA[f][1], fW1[j][1], acc1[f][j], 0, 0, 0);
        acc2[f][j] = MFMA16(fA[f][0], fW2[j][0], acc2[f][j], 0, 0, 0);
        acc2[f][j] = MFMA16(fA[f][1], fW2[j][1], acc2[f][j], 0, 0, 0);
      }
    __builtin_amdgcn_s_setprio(0);
    #pragma unroll
    for (int f = 0; f < 4; f++) {
      fA[f][0] = *(const short8*)(cA1 + arow + f * 1024 + kx0);
      fA[f][1] = *(const short8*)(cA1 + arow + f * 1024 + kx1);
    }
    wg_barrier();   // bar2: A1 reads done across waves

    // region 3: stage A1(u+2) -> cur; 32-MFMA cluster on A1; counted vmcnt
    if (s2) { glds16(gA1c0, Sb + 8192); glds16(gA1c1, Sb + 12288); }
    gA0c0 += 64; gA0c1 += 64; gA1c0 += 64; gA1c1 += 64;
    gW1c0 += 64; gW1c1 += 64; gW2c0 += 64; gW2c1 += 64;
    __builtin_amdgcn_s_setprio(1);
    #pragma unroll
    for (int f = 0; f < 4; f++)
      #pragma unroll
      for (int j = 0; j < 2; j++) {
        acc1[4 + f][j] = MFMA16(fA[f][0], fW1[j][0], acc1[4 + f][j], 0, 0, 0);
        acc1[4 + f][j] = MFMA16(fA[f][1], fW1[j][1], acc1[4 + f][j], 0, 0, 0);
        acc2[4 + f][j] = MFMA16(fA[f][0], fW2[j][0], acc2[4 + f][j], 0, 0, 0);
        acc2[4 + f][j] = MFMA16(fA[f][1], fW2[j][1], acc2[4 + f][j], 0, 0, 0);
      }
    __builtin_amdgcn_s_setprio(0);
    if (s2)      asm volatile("s_waitcnt vmcnt(8)" ::: "memory");
    else if (s1) asm volatile("s_waitcnt vmcnt(0)" ::: "memory");
    wg_barrier();   // bar3: tile u+1 fully in LDS
  }

  #pragma unroll
  for (int f = 0; f < 8; f++) {
    int row = m0 + (f >> 2) * 128 + wm * 64 + (f & 3) * 16 + quad * 4;
    #pragma unroll
    for (int j = 0; j < 2; j++) {
      int col = n0 + wn * 32 + j * 16 + r;
      float b1 = (col < 2730) ? bias[col] : 0.f;
      float b2 = (col < 2730) ? bias[2730 + col] : 0.f;
      #pragma unroll
      for (int rr = 0; rr < 4; rr++) {
        float h1 = acc1[f][j][rr] + b1;
        float h2 = acc2[f][j][rr] + b2;
        Hb[(size_t)(row + rr) * 2816 + col] = f2bf(silu_f(h1) * h2);
      }
    }
  }
}

// ---------- MFMA flash attention, spatial: seq=256, hd=64 ----------
// 512 threads per block, both q-halves in one block; threads 0-255 prep K
// (rmsnorm+rope), 256-511 copy V transposed.
#define KSS 72
#define VSS 264
#define PSS 40
__global__ __launch_bounds__(512) void attn_s_mfma(
    const u16* __restrict__ QKV,
    const float* __restrict__ qn_w, const float* __restrict__ kn_w,
    const float* __restrict__ cosT, const float* __restrict__ sinT,
    u16* __restrict__ AO) {
  __shared__ u16 Ks[256 * KSS];
  __shared__ u16 Vt[64 * VSS];
  __shared__ u16 Pl[8 * 32 * PSS];
  int pair = blockIdx.x;
  int s = pair >> 4, h = pair & 15;
  int tid = threadIdx.x, wid = tid >> 6, lane = tid & 63;
  int quad = lane >> 4, r = lane & 15;

  if (tid < 256) {
    int j = tid;
    size_t rowb = ((size_t)(s * 256 + j)) * 3072 + (size_t)h * 64;
    const short8* kr = (const short8*)(QKV + rowb + 1024);
    float xk[64]; float ssq = 0.f;
    #pragma unroll
    for (int cg = 0; cg < 8; cg++) {
      short8 kk = kr[cg];
      #pragma unroll
      for (int e = 0; e < 8; e++) { float v = bf2f((u16)kk[e]); xk[cg * 8 + e] = v; ssq += v * v; }
    }
    float rms = rsqrtf(ssq * (1.f / 64.f) + 1e-6f);
    short8 kq[8];
    #pragma unroll
    for (int d = 0; d < 32; d++) {
      float a = xk[d] * rms * kn_w[d];
      float b2 = xk[d + 32] * rms * kn_w[d + 32];
      u16 o0 = f2bf(a * cosT[j * 64 + d] - b2 * sinT[j * 64 + d]);
      u16 o1 = f2bf(b2 * cosT[j * 64 + 32 + d] + a * sinT[j * 64 + 32 + d]);
      kq[d >> 3][d & 7] = (short)o0;
      kq[(d + 32) >> 3][d & 7] = (short)o1;
    }
    #pragma unroll
    for (int cg = 0; cg < 8; cg++) *(short8*)(Ks + j * KSS + cg * 8) = kq[cg];
  } else {
    int j = tid - 256;
    size_t rowb = ((size_t)(s * 256 + j)) * 3072 + (size_t)h * 64;
    const short8* vr = (const short8*)(QKV + rowb + 2048);
    #pragma unroll
    for (int cg = 0; cg < 8; cg++) {
      short8 vv = vr[cg];
      #pragma unroll
      for (int e = 0; e < 8; e++) Vt[(cg * 8 + e) * VSS + j] = (u16)vv[e];
    }
  }

  int qbase = wid * 32;   // 8 waves cover 256 q rows
  short8 qa[2][2];
  float lrow[2][4];
  {
    float qv[2][2][8];
    float ssq[2] = {0.f, 0.f};
    #pragma unroll
    for (int i = 0; i < 2; i++) {
      int grow = s * 256 + qbase + i * 16 + r;
      #pragma unroll
      for (int kk = 0; kk < 2; kk++) {
        short8 qraw = *(const short8*)(QKV + (size_t)grow * 3072 + h * 64 + kk * 32 + quad * 8);
        #pragma unroll
        for (int e = 0; e < 8; e++) { float v = bf2f((u16)qraw[e]); qv[i][kk][e] = v; ssq[i] += v * v; }
      }
    }
    #pragma unroll
    for (int i = 0; i < 2; i++) {
      float sv = ssq[i];
      sv += __shfl_xor(sv, 16);
      sv += __shfl_xor(sv, 32);
      float rms = rsqrtf(sv * (1.f / 64.f) + 1e-6f);
      int qrow = qbase + i * 16 + r;
      #pragma unroll
      for (int e = 0; e < 8; e++) {
        int d0 = quad * 8 + e;
        float a = qv[i][0][e] * rms * qn_w[d0];
        float b2 = qv[i][1][e] * rms * qn_w[d0 + 32];
        qa[i][0][e] = (short)f2bf(a * cosT[qrow * 64 + d0] - b2 * sinT[qrow * 64 + d0]);
        qa[i][1][e] = (short)f2bf(b2 * cosT[qrow * 64 + 32 + d0] + a * sinT[qrow * 64 + 32 + d0]);
      }
    }
  }
  __syncthreads();

  f32x4 zero = {0.f, 0.f, 0.f, 0.f};
  f32x4 acc[2][16];
  #pragma unroll
  for (int i = 0; i < 2; i++)
    #pragma unroll
    for (int j = 0; j < 16; j++) acc[i][j] = zero;
  #pragma unroll
  for (int kk = 0; kk < 2; kk++) {
    #pragma unroll
    for (int j = 0; j < 16; j++) {
      short8 bfr = *(const short8*)(Ks + (j * 16 + r) * KSS + kk * 32 + quad * 8);
      acc[0][j] = MFMA16(qa[0][kk], bfr, acc[0][j], 0, 0, 0);
      acc[1][j] = MFMA16(qa[1][kk], bfr, acc[1][j], 0, 0, 0);
    }
  }

  #pragma unroll
  for (int i = 0; i < 2; i++) {
    #pragma unroll
    for (int rr = 0; rr < 4; rr++) {
      float mx = acc[i][0][rr];
      #pragma unroll
      for (int j = 1; j < 16; j++) mx = fmaxf(mx, acc[i][j][rr]);
      #pragma unroll
      for (int msk = 1; msk < 16; msk <<= 1) mx = fmaxf(mx, __shfl_xor(mx, msk));
      float ls = 0.f;
      #pragma unroll
      for (int j = 0; j < 16; j++) { float p = __expf((acc[i][j][rr] - mx) * 0.125f); acc[i][j][rr] = p; ls += p; }
      #pragma unroll
      for (int msk = 1; msk < 16; msk <<= 1) ls += __shfl_xor(ls, msk);
      lrow[i][rr] = ls;
    }
  }

  f32x4 oacc[2][4];
  #pragma unroll
  for (int i = 0; i < 2; i++)
    #pragma unroll
    for (int j = 0; j < 4; j++) oacc[i][j] = zero;
  u16* plw = Pl + wid * 32 * PSS;
  #pragma unroll
  for (int kk = 0; kk < 8; kk++) {
    #pragma unroll
    for (int i = 0; i < 2; i++)
      #pragma unroll
      for (int jj = 0; jj < 2; jj++) {
        int j = kk * 2 + jj;
        #pragma unroll
        for (int rr = 0; rr < 4; rr++)
          plw[(i * 16 + quad * 4 + rr) * PSS + jj * 16 + r] = f2bf(acc[i][j][rr]);
      }
    short8 pa0 = *(const short8*)(plw + r * PSS + quad * 8);
    short8 pa1 = *(const short8*)(plw + (16 + r) * PSS + quad * 8);
    #pragma unroll
    for (int j4 = 0; j4 < 4; j4++) {
      short8 vfr = *(const short8*)(Vt + (j4 * 16 + r) * VSS + kk * 32 + quad * 8);
      oacc[0][j4] = MFMA16(pa0, vfr, oacc[0][j4], 0, 0, 0);
      oacc[1][j4] = MFMA16(pa1, vfr, oacc[1][j4], 0, 0, 0);
    }
  }

  #pragma unroll
  for (int i = 0; i < 2; i++) {
    #pragma unroll
    for (int rr = 0; rr < 4; rr++) {
      float inv = 1.f / lrow[i][rr];
      int row = s * 256 + qbase + i * 16 + quad * 4 + rr;
      #pragma unroll
      for (int j4 = 0; j4 < 4; j4++)
        AO[(size_t)row * 1024 + h * 64 + j4 * 16 + r] = f2bf(oacc[i][j4][rr] * inv);
    }
  }
}

// ---------- temporal attention: seq=16, block per (b,l), thread = (head, t) ----------
__global__ __launch_bounds__(256) void attn_t_kernel(
    const u16* __restrict__ QKV,
    const float* __restrict__ qn_w, const float* __restrict__ kn_w,
    const float* __restrict__ cosT, const float* __restrict__ sinT,
    u16* __restrict__ AO) {
  __shared__ u16 kb[256 * 64];
  __shared__ u16 vb[256 * 64];
  int bl = blockIdx.x;
  int tid = threadIdx.x;
  int h = tid >> 4, t = tid & 15;
  size_t rowbase = ((size_t)(bl * 16 + t)) * 3072;
  int slot = h * 16 + t;
  {
    const u16* kr = QKV + rowbase + 1024 + h * 64;
    float xk[64]; float ss = 0.f;
    #pragma unroll
    for (int d = 0; d < 64; d++) { xk[d] = bf2f(kr[d]); ss += xk[d] * xk[d]; }
    float rms = rsqrtf(ss * (1.f / 64.f) + 1e-6f);
    #pragma unroll
    for (int d = 0; d < 64; d++) xk[d] *= rms * kn_w[d];
    #pragma unroll
    for (int d = 0; d < 32; d++) {
      float a = xk[d], bb = xk[d + 32];
      kb[slot * 64 + d]      = f2bf(a * cosT[t * 64 + d]       - bb * sinT[t * 64 + d]);
      kb[slot * 64 + 32 + d] = f2bf(bb * cosT[t * 64 + 32 + d] + a * sinT[t * 64 + 32 + d]);
    }
    const u16* vr = QKV + rowbase + 2048 + h * 64;
    #pragma unroll
    for (int d = 0; d < 64; d++) vb[slot * 64 + d] = vr[d];
  }
  float q[64];
  {
    const u16* qr = QKV + rowbase + h * 64;
    float ss = 0.f;
    #pragma unroll
    for (int d = 0; d < 64; d++) { q[d] = bf2f(qr[d]); ss += q[d] * q[d]; }
    float rms = rsqrtf(ss * (1.f / 64.f) + 1e-6f);
    #pragma unroll
    for (int d = 0; d < 64; d++) q[d] *= rms * qn_w[d];
    #pragma unroll
    for (int d = 0; d < 32; d++) {
      float a = q[d], bb = q[d + 32];
      q[d]      = a * cosT[t * 64 + d]       - bb * sinT[t * 64 + d];
      q[d + 32] = bb * cosT[t * 64 + 32 + d] + a * sinT[t * 64 + 32 + d];
    }
  }
  __syncthreads();
  float scv[16]; float mx = -1e30f;
  #pragma unroll
  for (int j = 0; j < 16; j++) {
    float sc = 0.f;
    const short8* krow = (const short8*)(kb + (h * 16 + j) * 64);
    #pragma unroll
    for (int vv = 0; vv < 8; vv++) {
      short8 kk = krow[vv];
      #pragma unroll
      for (int e = 0; e < 8; e++) sc += q[vv * 8 + e] * bf2f((u16)kk[e]);
    }
    scv[j] = sc * 0.125f;
    mx = fmaxf(mx, scv[j]);
  }
  float ssum = 0.f;
  #pragma unroll
  for (int j = 0; j < 16; j++) { scv[j] = __expf(scv[j] - mx); ssum += scv[j]; }
  float inv = 1.f / ssum;
  float o[64];
  #pragma unroll
  for (int d = 0; d < 64; d++) o[d] = 0.f;
  #pragma unroll
  for (int j = 0; j < 16; j++) {
    const short8* vrow = (const short8*)(vb + (h * 16 + j) * 64);
    #pragma unroll
    for (int vv = 0; vv < 8; vv++) {
      short8 vk = vrow[vv];
      #pragma unroll
      for (int e = 0; e < 8; e++) o[vv * 8 + e] += scv[j] * bf2f((u16)vk[e]);
    }
  }
  u16* op = AO + ((size_t)(bl * 16 + t)) * 1024 + h * 64;
  #pragma unroll
  for (int d = 0; d < 64; d++) op[d] = f2bf(o[d] * inv);
}

// =====================================================================
extern "C" void kernel_launch(void* const* d_in, const int* in_sizes, int n_in,
                              void* d_out, int out_size, void* d_ws, size_t ws_size,
                              hipStream_t stream) {
  const float* x        = (const float*)d_in[0];
  const float* c        = (const float*)d_in[1];
  const float* cos_s    = (const float*)d_in[2];
  const float* sin_s    = (const float*)d_in[3];
  const float* cos_t    = (const float*)d_in[4];
  const float* sin_t    = (const float*)d_in[5];
  const float* norm1w   = (const float*)d_in[6];
  const float* norm2w   = (const float*)d_in[7];
  const float* norm3w   = (const float*)d_in[8];
  const float* qkv_s_w  = (const float*)d_in[9];
  const float* qkv_s_b  = (const float*)d_in[10];
  const float* qn_s_w   = (const float*)d_in[11];
  const float* kn_s_w   = (const float*)d_in[12];
  const float* proj_s_w = (const float*)d_in[13];
  const float* proj_s_b = (const float*)d_in[14];
  const float* qkv_t_w  = (const float*)d_in[15];
  const float* qkv_t_b  = (const float*)d_in[16];
  const float* qn_t_w   = (const float*)d_in[17];
  const float* kn_t_w   = (const float*)d_in[18];
  const float* proj_t_w = (const float*)d_in[19];
  const float* proj_t_b = (const float*)d_in[20];
  const float* w12_w    = (const float*)d_in[21];
  const float* w12_b    = (const float*)d_in[22];
  const float* w3_w     = (const float*)d_in[23];
  const float* w3_b     = (const float*)d_in[24];
  const float* ada_w    = (const float*)d_in[25];
  const float* ada_b    = (const float*)d_in[26];
  float* out = (float*)d_out;

  // ---- workspace layout (unchanged) ----
  char* wsp = (char*)d_ws;
  size_t off = 0;
  auto alloc = [&](size_t bytes) { size_t p = off; off += (bytes + 255) & ~(size_t)255; return p; };
  float* modsb = (float*)(wsp + alloc(2 * 9216 * 4));
  u16*   BIG   = (u16*)  (wsp + alloc((size_t)8192 * 3072 * 2));  // QKV (st1,2) / Hb 8192x2816 (st3)
  char*  XnP   = (char*) (wsp + alloc((size_t)8192 * 1024 * 4));  // Xn bf16
  u16*   AO    = (u16*)  (wsp + alloc((size_t)8192 * 1024 * 2));
  u16*   Wq    = (u16*)  (wsp + alloc((size_t)3072 * 1024 * 2));
  u16*   Wp    = (u16*)  (wsp + alloc((size_t)2816 * 1024 * 2));
  u16*   W3b   = (u16*)  (wsp + alloc((size_t)1024 * 2816 * 2));
  u16* W1p = Wq;
  u16* W2p = Wp;
  u16* Xn  = (u16*)XnP;
  float* Xcur = out;   // residual stream lives in d_out

  dim3 blk(256);
  dim3 blk512(512);
  mods_kernel<<<2304, blk, 0, stream>>>(c, ada_w, ada_b, modsb);

  // ---- stage 1: spatial attention ----
  {
    int n0 = 3072 * 1024, n1 = 1024 * 1024;
    cvt2_kernel<<<(n0 + n1) / 1024, blk, 0, stream>>>(qkv_s_w, Wq, n0, proj_s_w, Wp, n1);
  }
  norm_mod_kernel<<<8192, blk, 0, stream>>>(x, Xn, norm1w, modsb, 0, 0);
  // QKV: N=3072 -> 32 x 24 = 768 blocks = 3 exact dispatch rounds
  gemm256_n128<1><<<dim3(32 * 24), blk512, 0, stream>>>(Xn, Wq, qkv_s_b, BIG, 1024, 3072, nullptr, nullptr, 0);
  attn_s_mfma<<<dim3(512), blk512, 0, stream>>>(BIG, qn_s_w, kn_s_w, cos_s, sin_s, AO);
  // proj + residual fused: Xcur = x + g2 * (AO @ Wp^T + b)
  gemm256_n128<2><<<dim3(32 * 8), blk512, 0, stream>>>(AO, Wp, proj_s_b, Xcur, 1024, 1024, x, modsb, 2);

  // ---- stage 2: temporal attention (rows in (b,l,t) order) ----
  {
    int n0 = 3072 * 1024, n1 = 1024 * 1024;
    cvt2_kernel<<<(n0 + n1) / 1024, blk, 0, stream>>>(qkv_t_w, Wq, n0, proj_t_w, Wp, n1);
  }
  norm_mod_kernel<<<8192, blk, 0, stream>>>(Xcur, Xn, norm2w, modsb, 3, 1);
  gemm256_n128<1><<<dim3(32 * 24), blk512, 0, stream>>>(Xn, Wq, qkv_t_b, BIG, 1024, 3072, nullptr, nullptr, 0);
  attn_t_kernel<<<512, blk, 0, stream>>>(BIG, qn_t_w, kn_t_w, cos_t, sin_t, AO);
  // proj + residual fused with (b,l,t)->(b,t,l) transpose: Xcur = Xcur + g5 * T(proj)
  gemm256_n128<3><<<dim3(32 * 8), blk512, 0, stream>>>(AO, Wp, proj_t_b, Xcur, 1024, 1024, Xcur, modsb, 5);

  // ---- stage 3: SwiGLU MLP (HFF 2730 padded to 2816) ----
  {
    int tot = 2 * 2816 * 1024 + 1024 * 2816;
    cvt3_kernel<<<(tot + 255) / 256, blk, 0, stream>>>(w12_w, W1p, W2p, w3_w, W3b);
  }
  norm_mod_kernel<<<8192, blk, 0, stream>>>(Xcur, Xn, norm3w, modsb, 6, 0);
  gemm256_w12<<<dim3(32 * 22), blk512, 0, stream>>>(Xn, W1p, W2p, w12_b, BIG);
  // w3 + residual fused: out = Xcur + g8 * (Hb @ W3^T + b)  (K=2816 -> nk=44, even)
  gemm256_n128<2><<<dim3(32 * 8), blk512, 0, stream>>>(BIG, W3b, w3_b, out, 2816, 1024, Xcur, modsb, 8);
}